// Round 9
// baseline (4934.661 us; speedup 1.0000x reference)
//
#include <hip/hip_runtime.h>
#include <hip/hip_bf16.h>

// CLIP ViT-B/16 visual forward — Round 8: K-split wave partition in GEMM.
// 64x128 tile, BK=64, 4 waves = (K-half x N-half), each wave 64x64 output on a
// 32-wide K slice -> 8 ds_read_b128 per 16 MFMA (1.5x less LDS traffic than
// N-split). Epilogue LDS reduce combines K-halves. Attention/LN unchanged.

#define LAYERS 12
#define DMODEL 768
#define NHEADS 12
#define DHEAD  64
#define FFDIM  3072
#define BATCH  32
#define SEQ    197
#define NPATCH 196
#define OUTD   512
#define MROWS  (BATCH * SEQ)   // 6304
#define MPAD   6400            // 50 * 128
#define SPAD   208             // 13 * 16 (padded seq)
#define VSTR   208

typedef __attribute__((ext_vector_type(4))) float f32x4;
typedef __attribute__((ext_vector_type(8))) short bf16x8;

enum { M_F32 = 0, M_ACC = 1, M_GELU = 2, M_PATCH = 3, M_QKVB = 4 };

__device__ __forceinline__ float b2f(short s) {
    unsigned u = ((unsigned)(unsigned short)s) << 16;
    return __builtin_bit_cast(float, u);
}
__device__ __forceinline__ short f2b(float f) {
    __hip_bfloat16 h = __float2bfloat16(f);
    return __builtin_bit_cast(short, h);
}

__device__ __forceinline__ void gl2lds16(const void* g, void* l) {
    __builtin_amdgcn_global_load_lds(
        (const __attribute__((address_space(1))) void*)g,
        (__attribute__((address_space(3))) void*)l, 16, 0, 0);
}

// ---------------------------------------------------------------- weight cvt
__global__ __launch_bounds__(256) void cvt_bf16_kernel(
    const float* __restrict__ src, __hip_bfloat16* __restrict__ dst, long n)
{
    long i0 = ((long)blockIdx.x * 256 + threadIdx.x) * 4;
    long stride = (long)gridDim.x * 1024;
    for (long i = i0; i < n; i += stride) {
        float4 v = *reinterpret_cast<const float4*>(&src[i]);
        dst[i + 0] = __float2bfloat16(v.x);
        dst[i + 1] = __float2bfloat16(v.y);
        dst[i + 2] = __float2bfloat16(v.z);
        dst[i + 3] = __float2bfloat16(v.w);
    }
}

// ---------------------------------------------------------------- im2col
__global__ __launch_bounds__(256) void im2col_kernel(
    const float* __restrict__ x_inp, __hip_bfloat16* __restrict__ patches)
{
    int bp = blockIdx.x;                 // b*196 + p
    int b = bp / NPATCH, p = bp % NPATCH;
    int py = p / 14, px = p % 14;
    const float* xb = x_inp + (long)b * 3 * 224 * 224;
    for (int e = threadIdx.x; e < 768; e += 256) {
        int c = e >> 8, i = (e >> 4) & 15, j = e & 15;
        patches[(long)bp * 768 + e] =
            __float2bfloat16(xb[((long)c * 224 + py * 16 + i) * 224 + px * 16 + j]);
    }
}

__global__ __launch_bounds__(256) void cls_token_kernel(
    const float* __restrict__ cls_emb, const float* __restrict__ pos_emb,
    float* __restrict__ x)
{
    int b = blockIdx.x;
    for (int d = threadIdx.x; d < DMODEL; d += 256)
        x[(long)b * SEQ * DMODEL + d] = cls_emb[d] + pos_emb[d];
}

// ---------------------------------------------------------------- layernorm
template<int OB>
__global__ __launch_bounds__(256) void ln_kernel(
    const float* __restrict__ in, void* __restrict__ out,
    const float* __restrict__ w, const float* __restrict__ bb,
    long in_stride, long out_stride)
{
    int row = blockIdx.x;
    const float* xr = in + (long)row * in_stride;
    int t = threadIdx.x;
    int lane = t & 63, wid = t >> 6;
    __shared__ float red[8];

    float v[3];
    float s = 0.f;
    #pragma unroll
    for (int i = 0; i < 3; ++i) { v[i] = xr[t + i * 256]; s += v[i]; }
    #pragma unroll
    for (int off = 32; off; off >>= 1) s += __shfl_xor(s, off);
    if (lane == 0) red[wid] = s;
    __syncthreads();
    float mean = (red[0] + red[1] + red[2] + red[3]) * (1.0f / DMODEL);
    float sq = 0.f;
    #pragma unroll
    for (int i = 0; i < 3; ++i) { float d = v[i] - mean; sq += d * d; }
    #pragma unroll
    for (int off = 32; off; off >>= 1) sq += __shfl_xor(sq, off);
    if (lane == 0) red[4 + wid] = sq;
    __syncthreads();
    float rstd = rsqrtf((red[4] + red[5] + red[6] + red[7]) * (1.0f / DMODEL) + 1e-5f);
    #pragma unroll
    for (int i = 0; i < 3; ++i) {
        int d = t + i * 256;
        float o = (v[i] - mean) * rstd * w[d] + bb[d];
        if (OB) ((__hip_bfloat16*)out)[(long)row * out_stride + d] = __float2bfloat16(o);
        else    ((float*)out)[(long)row * out_stride + d] = o;
    }
}

// ---------------------------------------------------------------- bf16 GEMM
// C[M,N] = A[M,K] @ W[N,K]^T (+bias / epilogue per MODE).
// Tile 64x128, BK=64. Waves: wkh = K-half (32 of 64), wnh = N-half (64 cols);
// each wave computes the FULL 64-row x 64-col output on its K slice
// (4x4 16x16 frags = 16 MFMA, 8 ds_read_b128). K-halves combined via a
// padded LDS reduce in the epilogue. 2-buffer LDS (48KB), one barrier per
// K-step, bijective XCD-chunked 1D grid swizzle. Chunk swizzle: c ^= row&7.
template<int MODE>
__global__ __launch_bounds__(256) void gemm_bf16(
    const __hip_bfloat16* __restrict__ A, const __hip_bfloat16* __restrict__ W,
    const float* __restrict__ bias, float* __restrict__ Cf,
    __hip_bfloat16* __restrict__ Cb, int M, int N, int K, int NB,
    const float* __restrict__ pos)
{
    __shared__ __align__(16) char smem[49152];
    char* A0 = smem;            // 8KB  (64x64 bf16)
    char* A1 = smem + 8192;
    char* B0 = smem + 16384;    // 16KB (128x64 bf16)
    char* B1 = smem + 32768;

    int tid = threadIdx.x, lane = tid & 63, wv = tid >> 6;

    // bijective XCD-chunked remap (m204)
    int nwg = gridDim.x, bid = blockIdx.x;
    int qq = nwg >> 3, rr = nwg & 7;
    int xcd = bid & 7, idx = bid >> 3;
    int newid = (xcd < rr ? xcd * (qq + 1) : rr * (qq + 1) + (xcd - rr) * qq) + idx;

    int bm = (newid / NB) * 64, bn = (newid % NB) * 128;
    int wkh = wv >> 1, wnh = wv & 1;
    f32x4 acc[4][4] = {};

    // staging: thread t -> (row sr = t/8, chunk sc = t%8) within a 32-row pass;
    // storage chunk sc holds logical chunk sc ^ (sr&7); rows sr+32k keep sr&7.
    int sr = tid >> 3, sc = tid & 7;
    int c_log = sc ^ (sr & 7);
    const short* Ag = (const short*)A + (long)(bm + sr) * K + (c_log << 3);
    const short* Bg = (const short*)W + (long)(bn + sr) * K + (c_log << 3);
    const long K32 = (long)32 * K;

    // MFMA fragment read offsets (elements); this wave's k-chunk = wkh*4 + lg
    int lg = lane >> 4, lr16 = lane & 15;
    int kc = (wkh << 2) | lg;
    int aoff[4], boff[4];
    #pragma unroll
    for (int i = 0; i < 4; ++i) {
        int ra = i * 16 + lr16;
        aoff[i] = (ra << 6) + ((kc ^ (ra & 7)) << 3);
    }
    #pragma unroll
    for (int j = 0; j < 4; ++j) {
        int rb = wnh * 64 + j * 16 + lr16;
        boff[j] = (rb << 6) + ((kc ^ (rb & 7)) << 3);
    }

    const int KT = K >> 6;
    // prologue: stage tile 0 into buf 0 (A: 2 passes, B: 4 passes)
    gl2lds16(Ag,           A0 + tid * 16);
    gl2lds16(Ag + K32,     A0 + 4096 + tid * 16);
    gl2lds16(Bg,           B0 + tid * 16);
    gl2lds16(Bg + K32,     B0 + 4096 + tid * 16);
    gl2lds16(Bg + 2 * K32, B0 + 8192 + tid * 16);
    gl2lds16(Bg + 3 * K32, B0 + 12288 + tid * 16);
    __syncthreads();

    for (int t = 0; t < KT; ++t) {
        if (t + 1 < KT) {
            int ktn = (t + 1) << 6;
            char* Ad = (t & 1) ? A0 : A1;
            char* Bd = (t & 1) ? B0 : B1;
            gl2lds16(Ag + ktn,           Ad + tid * 16);
            gl2lds16(Ag + K32 + ktn,     Ad + 4096 + tid * 16);
            gl2lds16(Bg + ktn,           Bd + tid * 16);
            gl2lds16(Bg + K32 + ktn,     Bd + 4096 + tid * 16);
            gl2lds16(Bg + 2 * K32 + ktn, Bd + 8192 + tid * 16);
            gl2lds16(Bg + 3 * K32 + ktn, Bd + 12288 + tid * 16);
        }
        const short* Ab = (const short*)((t & 1) ? A1 : A0);
        const short* Bb = (const short*)((t & 1) ? B1 : B0);
        bf16x8 af[4], bfr[4];
        #pragma unroll
        for (int i = 0; i < 4; ++i)
            af[i] = *reinterpret_cast<const bf16x8*>(&Ab[aoff[i]]);
        #pragma unroll
        for (int j = 0; j < 4; ++j)
            bfr[j] = *reinterpret_cast<const bf16x8*>(&Bb[boff[j]]);
        #pragma unroll
        for (int mi = 0; mi < 4; ++mi)
            #pragma unroll
            for (int ni = 0; ni < 4; ++ni)
                acc[mi][ni] = __builtin_amdgcn_mfma_f32_16x16x32_bf16(
                    af[mi], bfr[ni], acc[mi][ni], 0, 0, 0);
        __syncthreads();
    }

    // cross-K-half reduce via LDS (stride 72 f32: 16B-aligned b128, ~4-way)
    float* red = (float*)smem;
    float* area = red + wnh * (64 * 72);
    if (wkh == 1) {
        #pragma unroll
        for (int ni = 0; ni < 4; ++ni) {
            int cl = ni * 16 + lr16;
            #pragma unroll
            for (int mi = 0; mi < 4; ++mi)
                *reinterpret_cast<f32x4*>(&area[cl * 72 + mi * 16 + lg * 4]) = acc[mi][ni];
        }
    }
    __syncthreads();
    if (wkh == 1) return;

    #pragma unroll
    for (int ni = 0; ni < 4; ++ni) {
        int cl = ni * 16 + lr16;
        #pragma unroll
        for (int mi = 0; mi < 4; ++mi)
            acc[mi][ni] += *reinterpret_cast<const f32x4*>(&area[cl * 72 + mi * 16 + lg * 4]);
    }

    #pragma unroll
    for (int mi = 0; mi < 4; ++mi) {
        int row0 = bm + mi * 16 + lg * 4;
        #pragma unroll
        for (int ni = 0; ni < 4; ++ni) {
            int col = bn + wnh * 64 + ni * 16 + lr16;
            #pragma unroll
            for (int r = 0; r < 4; ++r) {
                int row = row0 + r;
                if (row >= M) continue;
                float v = acc[mi][ni][r];
                if (MODE == M_PATCH) {
                    int pb = row / 196, pp = row - pb * 196;
                    Cf[((long)(pb * SEQ + 1 + pp)) * DMODEL + col] =
                        v + pos[(long)(1 + pp) * DMODEL + col];
                } else {
                    v += bias[col];
                    long idx2 = (long)row * N + col;
                    if (MODE == M_F32)      Cf[idx2] = v;
                    else if (MODE == M_ACC) Cf[idx2] += v;
                    else if (MODE == M_QKVB) Cb[idx2] = __float2bfloat16(v);
                    else if (MODE == M_GELU)
                        Cb[idx2] = __float2bfloat16(v / (1.f + __expf(-1.702f * v)));
                }
            }
        }
    }
}

// ---------------------------------------------------------------- attention
// Fused MFMA attention: one block (256 thr, 4 waves) per (b,h).
__global__ __launch_bounds__(256) void attn_kernel(
    const __hip_bfloat16* __restrict__ qkv,  // [MPAD, 2304] bf16
    __hip_bfloat16* __restrict__ o)          // [MPAD, 768]
{
    int bh = blockIdx.x;
    int b = bh / NHEADS, h = bh % NHEADS;
    int tid = threadIdx.x, lane = tid & 63, wv = tid >> 6;
    __shared__ short Ks[SPAD * 64];
    __shared__ short Vt[64 * VSTR];
    __shared__ short Ps[4][16 * VSTR];
    const short* base = (const short*)qkv + (long)b * SEQ * 2304;

    for (int idx = tid; idx < SPAD * 8; idx += 256) {
        int r = idx >> 3, c = idx & 7;
        int4 val = make_int4(0, 0, 0, 0);
        if (r < SEQ)
            val = *reinterpret_cast<const int4*>(base + (long)r * 2304 + 768 + h * 64 + c * 8);
        *reinterpret_cast<int4*>(&Ks[r * 64 + ((c ^ (r & 7)) << 3)]) = val;
    }
    for (int idx = tid; idx < SPAD * 64; idx += 256) {
        int k = idx >> 6, d = idx & 63;
        short v = (k < SEQ) ? base[(long)k * 2304 + 1536 + h * 64 + d] : (short)0;
        Vt[d * VSTR + k] = v;
    }
    __syncthreads();

    int lg = lane >> 4, lr = lane & 15;
    short* Pw = Ps[wv];

    for (int ch = wv; ch < 13; ch += 4) {
        int q0 = ch * 16;
        const short* qp = (const short*)qkv +
            ((long)(b * SEQ) + q0 + lr) * 2304 + h * 64 + (lg << 3);
        bf16x8 qa = *reinterpret_cast<const bf16x8*>(qp);
        bf16x8 qb = *reinterpret_cast<const bf16x8*>(qp + 32);

        f32x4 sc[13];
        #pragma unroll
        for (int f = 0; f < 13; ++f) sc[f] = (f32x4){0.f, 0.f, 0.f, 0.f};
        #pragma unroll
        for (int f = 0; f < 13; ++f) {
            int row = f * 16 + lr;
            int sw = row & 7;
            const short* kr = &Ks[row * 64];
            bf16x8 k0 = *reinterpret_cast<const bf16x8*>(&kr[((lg + 0) ^ sw) << 3]);
            bf16x8 k1 = *reinterpret_cast<const bf16x8*>(&kr[((lg + 4) ^ sw) << 3]);
            sc[f] = __builtin_amdgcn_mfma_f32_16x16x32_bf16(qa, k0, sc[f], 0, 0, 0);
            sc[f] = __builtin_amdgcn_mfma_f32_16x16x32_bf16(qb, k1, sc[f], 0, 0, 0);
        }

        float mrow[4] = {-1e30f, -1e30f, -1e30f, -1e30f};
        #pragma unroll
        for (int f = 0; f < 13; ++f) {
            bool ok = f * 16 + lr < SEQ;
            #pragma unroll
            for (int r = 0; r < 4; ++r)
                if (ok) mrow[r] = fmaxf(mrow[r], sc[f][r] * 0.125f);
        }
        #pragma unroll
        for (int r = 0; r < 4; ++r)
            #pragma unroll
            for (int off = 8; off; off >>= 1)
                mrow[r] = fmaxf(mrow[r], __shfl_xor(mrow[r], off));
        float esum[4] = {0.f, 0.f, 0.f, 0.f};
        #pragma unroll
        for (int f = 0; f < 13; ++f) {
            bool ok = f * 16 + lr < SEQ;
            #pragma unroll
            for (int r = 0; r < 4; ++r) {
                float e = ok ? __expf(sc[f][r] * 0.125f - mrow[r]) : 0.f;
                sc[f][r] = e;
                esum[r] += e;
            }
        }
        #pragma unroll
        for (int r = 0; r < 4; ++r)
            #pragma unroll
            for (int off = 8; off; off >>= 1)
                esum[r] += __shfl_xor(esum[r], off);
        float inv[4];
        #pragma unroll
        for (int r = 0; r < 4; ++r) inv[r] = 1.0f / esum[r];

        #pragma unroll
        for (int f = 0; f < 13; ++f)
            #pragma unroll
            for (int r = 0; r < 4; ++r)
                Pw[(lg * 4 + r) * VSTR + f * 16 + lr] = f2b(sc[f][r] * inv[r]);

        f32x4 oa[4] = {};
        #pragma unroll
        for (int ks = 0; ks < 7; ++ks) {
            int kb = ks * 32 + (lg << 3);
            bf16x8 pa = {};
            if (kb < SPAD) pa = *reinterpret_cast<const bf16x8*>(&Pw[lr * VSTR + kb]);
            #pragma unroll
            for (int d = 0; d < 4; ++d) {
                bf16x8 vb = {};
                if (kb < SPAD)
                    vb = *reinterpret_cast<const bf16x8*>(&Vt[(d * 16 + lr) * VSTR + kb]);
                oa[d] = __builtin_amdgcn_mfma_f32_16x16x32_bf16(pa, vb, oa[d], 0, 0, 0);
            }
        }

        #pragma unroll
        for (int d = 0; d < 4; ++d)
            #pragma unroll
            for (int r = 0; r < 4; ++r) {
                int q = q0 + lg * 4 + r;
                if (q < SEQ)
                    o[((long)(b * SEQ + q)) * DMODEL + h * 64 + d * 16 + lr] =
                        __float2bfloat16(oa[d][r]);
            }
    }
}

// ---------------------------------------------------------------- final proj
__global__ __launch_bounds__(256) void proj_kernel(
    const float* __restrict__ cls_ln,  // [32,768]
    const float* __restrict__ proj,    // [768,512]
    float* __restrict__ out)           // [32,512]
{
    int idx = blockIdx.x * 256 + threadIdx.x;
    int m = idx >> 9, n = idx & 511;
    float s = 0.f;
    #pragma unroll 8
    for (int k = 0; k < 768; ++k)
        s += cls_ln[m * 768 + k] * proj[k * 512 + n];
    out[idx] = s;
}

// ---------------------------------------------------------------- launcher
extern "C" void kernel_launch(void* const* d_in, const int* in_sizes, int n_in,
                              void* d_out, int out_size, void* d_ws, size_t ws_size,
                              hipStream_t stream) {
    const float* x_inp    = (const float*)d_in[0];
    const float* conv_w   = (const float*)d_in[1];
    const float* cls_emb  = (const float*)d_in[2];
    const float* pos_emb  = (const float*)d_in[3];
    const float* ln_pre_w = (const float*)d_in[4];
    const float* ln_pre_b = (const float*)d_in[5];
    const float* ln1_w    = (const float*)d_in[6];
    const float* ln1_b    = (const float*)d_in[7];
    const float* qkv_w    = (const float*)d_in[8];
    const float* qkv_b    = (const float*)d_in[9];
    const float* out_w    = (const float*)d_in[10];
    const float* out_b    = (const float*)d_in[11];
    const float* ln2_w    = (const float*)d_in[12];
    const float* ln2_b    = (const float*)d_in[13];
    const float* fc1_w    = (const float*)d_in[14];
    const float* fc1_b    = (const float*)d_in[15];
    const float* fc2_w    = (const float*)d_in[16];
    const float* fc2_b    = (const float*)d_in[17];
    const float* ln_post_w= (const float*)d_in[18];
    const float* ln_post_b= (const float*)d_in[19];
    const float* proj     = (const float*)d_in[20];

    char* w = (char*)d_ws;
    __hip_bfloat16* wqkv = (__hip_bfloat16*)w; w += (size_t)LAYERS * 2304 * DMODEL * 2;
    __hip_bfloat16* wout = (__hip_bfloat16*)w; w += (size_t)LAYERS * DMODEL * DMODEL * 2;
    __hip_bfloat16* wfc1 = (__hip_bfloat16*)w; w += (size_t)LAYERS * FFDIM * DMODEL * 2;
    __hip_bfloat16* wfc2 = (__hip_bfloat16*)w; w += (size_t)LAYERS * DMODEL * FFDIM * 2;
    __hip_bfloat16* wconv= (__hip_bfloat16*)w; w += (size_t)DMODEL * DMODEL * 2;
    float* x             = (float*)w;          w += (size_t)MROWS * DMODEL * 4;
    __hip_bfloat16* y    = (__hip_bfloat16*)w; w += (size_t)MPAD * DMODEL * 2;
    __hip_bfloat16* qkvb = (__hip_bfloat16*)w; w += (size_t)MPAD * 2304 * 2;
    __hip_bfloat16* attno= (__hip_bfloat16*)w; w += (size_t)MPAD * DMODEL * 2;
    __hip_bfloat16* h1   = (__hip_bfloat16*)w; w += (size_t)MPAD * FFDIM * 2;
    __hip_bfloat16* patches = (__hip_bfloat16*)w; w += (size_t)NPATCH * BATCH * DMODEL * 2;
    float* clsb          = (float*)w;          w += (size_t)BATCH * DMODEL * 4;

    cvt_bf16_kernel<<<2048, 256, 0, stream>>>(qkv_w, wqkv, (long)LAYERS * 2304 * DMODEL);
    cvt_bf16_kernel<<<2048, 256, 0, stream>>>(out_w, wout, (long)LAYERS * DMODEL * DMODEL);
    cvt_bf16_kernel<<<2048, 256, 0, stream>>>(fc1_w, wfc1, (long)LAYERS * FFDIM * DMODEL);
    cvt_bf16_kernel<<<2048, 256, 0, stream>>>(fc2_w, wfc2, (long)LAYERS * DMODEL * FFDIM);
    cvt_bf16_kernel<<<512, 256, 0, stream>>>(conv_w, wconv, (long)DMODEL * DMODEL);

    im2col_kernel<<<NPATCH * BATCH, 256, 0, stream>>>(x_inp, patches);
    gemm_bf16<M_PATCH><<<98 * 6, 256, 0, stream>>>(
        patches, wconv, nullptr, x, nullptr, NPATCH * BATCH, DMODEL, DMODEL, 6, pos_emb);
    cls_token_kernel<<<BATCH, 256, 0, stream>>>(cls_emb, pos_emb, x);
    ln_kernel<0><<<MROWS, 256, 0, stream>>>(x, x, ln_pre_w, ln_pre_b, DMODEL, DMODEL);

    for (int l = 0; l < LAYERS; ++l) {
        ln_kernel<1><<<MROWS, 256, 0, stream>>>(x, y, ln1_w + l * DMODEL, ln1_b + l * DMODEL,
                                                DMODEL, DMODEL);
        gemm_bf16<M_QKVB><<<99 * 18, 256, 0, stream>>>(
            y, wqkv + (long)l * 2304 * DMODEL, qkv_b + (long)l * 2304, nullptr, qkvb,
            MROWS, 2304, DMODEL, 18, nullptr);
        attn_kernel<<<BATCH * NHEADS, 256, 0, stream>>>(qkvb, attno);
        gemm_bf16<M_ACC><<<99 * 6, 256, 0, stream>>>(
            attno, wout + (long)l * DMODEL * DMODEL, out_b + (long)l * DMODEL, x, nullptr,
            MROWS, DMODEL, DMODEL, 6, nullptr);
        ln_kernel<1><<<MROWS, 256, 0, stream>>>(x, y, ln2_w + l * DMODEL, ln2_b + l * DMODEL,
                                                DMODEL, DMODEL);
        gemm_bf16<M_GELU><<<99 * 24, 256, 0, stream>>>(
            y, wfc1 + (long)l * FFDIM * DMODEL, fc1_b + (long)l * FFDIM, nullptr, h1,
            MROWS, FFDIM, DMODEL, 24, nullptr);
        gemm_bf16<M_ACC><<<99 * 6, 256, 0, stream>>>(
            h1, wfc2 + (long)l * DMODEL * FFDIM, fc2_b + (long)l * DMODEL, x, nullptr,
            MROWS, DMODEL, FFDIM, 6, nullptr);
    }

    ln_kernel<0><<<BATCH, 256, 0, stream>>>(x, clsb, ln_post_w, ln_post_b,
                                            (long)SEQ * DMODEL, DMODEL);
    proj_kernel<<<(BATCH * OUTD) / 256, 256, 0, stream>>>(clsb, proj, (float*)d_out);
}

// Round 10
// 3590.953 us; speedup vs baseline: 1.3742x; 1.3742x over previous
//
#include <hip/hip_runtime.h>
#include <hip/hip_bf16.h>

// CLIP ViT-B/16 visual forward — Round 9: 128x128 tile, BK=64, 4 waves (2x2),
// 64x64 per wave (best FLOP/LDS-byte: 48KB per 2 MFLOP vs 72/1 in round 8).
// 2-buffer 64KB LDS, prefetch-next + one barrier per K-step, chunk^=row&7
// swizzle, XCD-chunked grid. Attention/LN/misc identical to round-8 source.

#define LAYERS 12
#define DMODEL 768
#define NHEADS 12
#define DHEAD  64
#define FFDIM  3072
#define BATCH  32
#define SEQ    197
#define NPATCH 196
#define OUTD   512
#define MROWS  (BATCH * SEQ)   // 6304
#define MPAD   6400            // 50 * 128
#define SPAD   208             // 13 * 16 (padded seq)
#define VSTR   208

typedef __attribute__((ext_vector_type(4))) float f32x4;
typedef __attribute__((ext_vector_type(8))) short bf16x8;

enum { M_F32 = 0, M_ACC = 1, M_GELU = 2, M_PATCH = 3, M_QKVB = 4 };

__device__ __forceinline__ float b2f(short s) {
    unsigned u = ((unsigned)(unsigned short)s) << 16;
    return __builtin_bit_cast(float, u);
}
__device__ __forceinline__ short f2b(float f) {
    __hip_bfloat16 h = __float2bfloat16(f);
    return __builtin_bit_cast(short, h);
}

__device__ __forceinline__ void gl2lds16(const void* g, void* l) {
    __builtin_amdgcn_global_load_lds(
        (const __attribute__((address_space(1))) void*)g,
        (__attribute__((address_space(3))) void*)l, 16, 0, 0);
}

// ---------------------------------------------------------------- weight cvt
__global__ __launch_bounds__(256) void cvt_bf16_kernel(
    const float* __restrict__ src, __hip_bfloat16* __restrict__ dst, long n)
{
    long i0 = ((long)blockIdx.x * 256 + threadIdx.x) * 4;
    long stride = (long)gridDim.x * 1024;
    for (long i = i0; i < n; i += stride) {
        float4 v = *reinterpret_cast<const float4*>(&src[i]);
        dst[i + 0] = __float2bfloat16(v.x);
        dst[i + 1] = __float2bfloat16(v.y);
        dst[i + 2] = __float2bfloat16(v.z);
        dst[i + 3] = __float2bfloat16(v.w);
    }
}

// ---------------------------------------------------------------- im2col
__global__ __launch_bounds__(256) void im2col_kernel(
    const float* __restrict__ x_inp, __hip_bfloat16* __restrict__ patches)
{
    int bp = blockIdx.x;                 // b*196 + p
    int b = bp / NPATCH, p = bp % NPATCH;
    int py = p / 14, px = p % 14;
    const float* xb = x_inp + (long)b * 3 * 224 * 224;
    for (int e = threadIdx.x; e < 768; e += 256) {
        int c = e >> 8, i = (e >> 4) & 15, j = e & 15;
        patches[(long)bp * 768 + e] =
            __float2bfloat16(xb[((long)c * 224 + py * 16 + i) * 224 + px * 16 + j]);
    }
}

__global__ __launch_bounds__(256) void cls_token_kernel(
    const float* __restrict__ cls_emb, const float* __restrict__ pos_emb,
    float* __restrict__ x)
{
    int b = blockIdx.x;
    for (int d = threadIdx.x; d < DMODEL; d += 256)
        x[(long)b * SEQ * DMODEL + d] = cls_emb[d] + pos_emb[d];
}

// ---------------------------------------------------------------- layernorm
template<int OB>
__global__ __launch_bounds__(256) void ln_kernel(
    const float* __restrict__ in, void* __restrict__ out,
    const float* __restrict__ w, const float* __restrict__ bb,
    long in_stride, long out_stride)
{
    int row = blockIdx.x;
    const float* xr = in + (long)row * in_stride;
    int t = threadIdx.x;
    int lane = t & 63, wid = t >> 6;
    __shared__ float red[8];

    float v[3];
    float s = 0.f;
    #pragma unroll
    for (int i = 0; i < 3; ++i) { v[i] = xr[t + i * 256]; s += v[i]; }
    #pragma unroll
    for (int off = 32; off; off >>= 1) s += __shfl_xor(s, off);
    if (lane == 0) red[wid] = s;
    __syncthreads();
    float mean = (red[0] + red[1] + red[2] + red[3]) * (1.0f / DMODEL);
    float sq = 0.f;
    #pragma unroll
    for (int i = 0; i < 3; ++i) { float d = v[i] - mean; sq += d * d; }
    #pragma unroll
    for (int off = 32; off; off >>= 1) sq += __shfl_xor(sq, off);
    if (lane == 0) red[4 + wid] = sq;
    __syncthreads();
    float rstd = rsqrtf((red[4] + red[5] + red[6] + red[7]) * (1.0f / DMODEL) + 1e-5f);
    #pragma unroll
    for (int i = 0; i < 3; ++i) {
        int d = t + i * 256;
        float o = (v[i] - mean) * rstd * w[d] + bb[d];
        if (OB) ((__hip_bfloat16*)out)[(long)row * out_stride + d] = __float2bfloat16(o);
        else    ((float*)out)[(long)row * out_stride + d] = o;
    }
}

// ---------------------------------------------------------------- bf16 GEMM
// C[M,N] = A[M,K] @ W[N,K]^T (+bias / epilogue per MODE).
// 128x128 tile, BK=64, 4 waves (2x2), each wave 64x64 out (4x4 16x16 frags):
// per K-step per wave 16 ds_read_b128 + 32 MFMA -> min LDS traffic per FLOP.
// 2-buffer LDS (64KB, 2 blocks/CU), one barrier per K-step, bijective
// XCD-chunked 1D grid swizzle. Chunk swizzle: slot = chunk ^ (row&7).
template<int MODE>
__global__ __launch_bounds__(256) void gemm_bf16(
    const __hip_bfloat16* __restrict__ A, const __hip_bfloat16* __restrict__ W,
    const float* __restrict__ bias, float* __restrict__ Cf,
    __hip_bfloat16* __restrict__ Cb, int M, int N, int K, int NB,
    const float* __restrict__ pos)
{
    __shared__ __align__(16) char smem[65536];
    char* A0 = smem;            // 16KB (128x64 bf16)
    char* A1 = smem + 16384;
    char* B0 = smem + 32768;    // 16KB (128x64 bf16)
    char* B1 = smem + 49152;

    int tid = threadIdx.x, lane = tid & 63, wv = tid >> 6;

    // bijective XCD-chunked remap (m204)
    int nwg = gridDim.x, bid = blockIdx.x;
    int qq = nwg >> 3, rr = nwg & 7;
    int xcd = bid & 7, idx = bid >> 3;
    int newid = (xcd < rr ? xcd * (qq + 1) : rr * (qq + 1) + (xcd - rr) * qq) + idx;

    int bm = (newid / NB) * 128, bn = (newid % NB) * 128;
    int wr = wv >> 1, wc = wv & 1;
    f32x4 acc[4][4] = {};

    // staging: thread t -> (row sr = t/8, chunk sc = t%8), 4 passes of 32 rows;
    // storage slot sc holds logical chunk sc ^ (sr&7) (rows +32 keep sr&7).
    int sr = tid >> 3, sc = tid & 7;
    int c_log = sc ^ (sr & 7);
    const short* Ag = (const short*)A + (long)(bm + sr) * K + (c_log << 3);
    const short* Bg = (const short*)W + (long)(bn + sr) * K + (c_log << 3);
    const long K32 = (long)32 * K;

    // MFMA fragment read offsets (elements); chunk for ksub s = s*4 + lg
    int lg = lane >> 4, lr16 = lane & 15;
    int aoff[2][4], boff[2][4];
    #pragma unroll
    for (int s = 0; s < 2; ++s) {
        int kc = (s << 2) | lg;
        #pragma unroll
        for (int i = 0; i < 4; ++i) {
            int ra = wr * 64 + i * 16 + lr16;
            aoff[s][i] = (ra << 6) + ((kc ^ (ra & 7)) << 3);
            int rb = wc * 64 + i * 16 + lr16;
            boff[s][i] = (rb << 6) + ((kc ^ (rb & 7)) << 3);
        }
    }

    const int KT = K >> 6;
    // prologue: stage tile 0 into buf 0 (A: 4 passes, B: 4 passes)
    #pragma unroll
    for (int p = 0; p < 4; ++p) {
        gl2lds16(Ag + p * K32, A0 + p * 4096 + tid * 16);
        gl2lds16(Bg + p * K32, B0 + p * 4096 + tid * 16);
    }
    __syncthreads();

    for (int t = 0; t < KT; ++t) {
        if (t + 1 < KT) {
            int ktn = (t + 1) << 6;
            char* Ad = (t & 1) ? A0 : A1;
            char* Bd = (t & 1) ? B0 : B1;
            #pragma unroll
            for (int p = 0; p < 4; ++p) {
                gl2lds16(Ag + p * K32 + ktn, Ad + p * 4096 + tid * 16);
                gl2lds16(Bg + p * K32 + ktn, Bd + p * 4096 + tid * 16);
            }
        }
        const short* Ab = (const short*)((t & 1) ? A1 : A0);
        const short* Bb = (const short*)((t & 1) ? B1 : B0);
        #pragma unroll
        for (int s = 0; s < 2; ++s) {
            bf16x8 af[4], bfr[4];
            #pragma unroll
            for (int i = 0; i < 4; ++i)
                af[i] = *reinterpret_cast<const bf16x8*>(&Ab[aoff[s][i]]);
            #pragma unroll
            for (int j = 0; j < 4; ++j)
                bfr[j] = *reinterpret_cast<const bf16x8*>(&Bb[boff[s][j]]);
            #pragma unroll
            for (int mi = 0; mi < 4; ++mi)
                #pragma unroll
                for (int ni = 0; ni < 4; ++ni)
                    acc[mi][ni] = __builtin_amdgcn_mfma_f32_16x16x32_bf16(
                        af[mi], bfr[ni], acc[mi][ni], 0, 0, 0);
        }
        __syncthreads();
    }

    #pragma unroll
    for (int mi = 0; mi < 4; ++mi) {
        int row0 = bm + wr * 64 + mi * 16 + lg * 4;
        #pragma unroll
        for (int ni = 0; ni < 4; ++ni) {
            int col = bn + wc * 64 + ni * 16 + lr16;
            #pragma unroll
            for (int r = 0; r < 4; ++r) {
                int row = row0 + r;
                if (row >= M) continue;
                float v = acc[mi][ni][r];
                if (MODE == M_PATCH) {
                    int pb = row / 196, pp = row - pb * 196;
                    Cf[((long)(pb * SEQ + 1 + pp)) * DMODEL + col] =
                        v + pos[(long)(1 + pp) * DMODEL + col];
                } else {
                    v += bias[col];
                    long idx2 = (long)row * N + col;
                    if (MODE == M_F32)      Cf[idx2] = v;
                    else if (MODE == M_ACC) Cf[idx2] += v;
                    else if (MODE == M_QKVB) Cb[idx2] = __float2bfloat16(v);
                    else if (MODE == M_GELU)
                        Cb[idx2] = __float2bfloat16(v / (1.f + __expf(-1.702f * v)));
                }
            }
        }
    }
}

// ---------------------------------------------------------------- attention
// Fused MFMA attention: one block (256 thr, 4 waves) per (b,h).
__global__ __launch_bounds__(256) void attn_kernel(
    const __hip_bfloat16* __restrict__ qkv,  // [MPAD, 2304] bf16
    __hip_bfloat16* __restrict__ o)          // [MPAD, 768]
{
    int bh = blockIdx.x;
    int b = bh / NHEADS, h = bh % NHEADS;
    int tid = threadIdx.x, lane = tid & 63, wv = tid >> 6;
    __shared__ short Ks[SPAD * 64];
    __shared__ short Vt[64 * VSTR];
    __shared__ short Ps[4][16 * VSTR];
    const short* base = (const short*)qkv + (long)b * SEQ * 2304;

    for (int idx = tid; idx < SPAD * 8; idx += 256) {
        int r = idx >> 3, c = idx & 7;
        int4 val = make_int4(0, 0, 0, 0);
        if (r < SEQ)
            val = *reinterpret_cast<const int4*>(base + (long)r * 2304 + 768 + h * 64 + c * 8);
        *reinterpret_cast<int4*>(&Ks[r * 64 + ((c ^ (r & 7)) << 3)]) = val;
    }
    for (int idx = tid; idx < SPAD * 64; idx += 256) {
        int k = idx >> 6, d = idx & 63;
        short v = (k < SEQ) ? base[(long)k * 2304 + 1536 + h * 64 + d] : (short)0;
        Vt[d * VSTR + k] = v;
    }
    __syncthreads();

    int lg = lane >> 4, lr = lane & 15;
    short* Pw = Ps[wv];

    for (int ch = wv; ch < 13; ch += 4) {
        int q0 = ch * 16;
        const short* qp = (const short*)qkv +
            ((long)(b * SEQ) + q0 + lr) * 2304 + h * 64 + (lg << 3);
        bf16x8 qa = *reinterpret_cast<const bf16x8*>(qp);
        bf16x8 qb = *reinterpret_cast<const bf16x8*>(qp + 32);

        f32x4 sc[13];
        #pragma unroll
        for (int f = 0; f < 13; ++f) sc[f] = (f32x4){0.f, 0.f, 0.f, 0.f};
        #pragma unroll
        for (int f = 0; f < 13; ++f) {
            int row = f * 16 + lr;
            int sw = row & 7;
            const short* kr = &Ks[row * 64];
            bf16x8 k0 = *reinterpret_cast<const bf16x8*>(&kr[((lg + 0) ^ sw) << 3]);
            bf16x8 k1 = *reinterpret_cast<const bf16x8*>(&kr[((lg + 4) ^ sw) << 3]);
            sc[f] = __builtin_amdgcn_mfma_f32_16x16x32_bf16(qa, k0, sc[f], 0, 0, 0);
            sc[f] = __builtin_amdgcn_mfma_f32_16x16x32_bf16(qb, k1, sc[f], 0, 0, 0);
        }

        float mrow[4] = {-1e30f, -1e30f, -1e30f, -1e30f};
        #pragma unroll
        for (int f = 0; f < 13; ++f) {
            bool ok = f * 16 + lr < SEQ;
            #pragma unroll
            for (int r = 0; r < 4; ++r)
                if (ok) mrow[r] = fmaxf(mrow[r], sc[f][r] * 0.125f);
        }
        #pragma unroll
        for (int r = 0; r < 4; ++r)
            #pragma unroll
            for (int off = 8; off; off >>= 1)
                mrow[r] = fmaxf(mrow[r], __shfl_xor(mrow[r], off));
        float esum[4] = {0.f, 0.f, 0.f, 0.f};
        #pragma unroll
        for (int f = 0; f < 13; ++f) {
            bool ok = f * 16 + lr < SEQ;
            #pragma unroll
            for (int r = 0; r < 4; ++r) {
                float e = ok ? __expf(sc[f][r] * 0.125f - mrow[r]) : 0.f;
                sc[f][r] = e;
                esum[r] += e;
            }
        }
        #pragma unroll
        for (int r = 0; r < 4; ++r)
            #pragma unroll
            for (int off = 8; off; off >>= 1)
                esum[r] += __shfl_xor(esum[r], off);
        float inv[4];
        #pragma unroll
        for (int r = 0; r < 4; ++r) inv[r] = 1.0f / esum[r];

        #pragma unroll
        for (int f = 0; f < 13; ++f)
            #pragma unroll
            for (int r = 0; r < 4; ++r)
                Pw[(lg * 4 + r) * VSTR + f * 16 + lr] = f2b(sc[f][r] * inv[r]);

        f32x4 oa[4] = {};
        #pragma unroll
        for (int ks = 0; ks < 7; ++ks) {
            int kb = ks * 32 + (lg << 3);
            bf16x8 pa = {};
            if (kb < SPAD) pa = *reinterpret_cast<const bf16x8*>(&Pw[lr * VSTR + kb]);
            #pragma unroll
            for (int d = 0; d < 4; ++d) {
                bf16x8 vb = {};
                if (kb < SPAD)
                    vb = *reinterpret_cast<const bf16x8*>(&Vt[(d * 16 + lr) * VSTR + kb]);
                oa[d] = __builtin_amdgcn_mfma_f32_16x16x32_bf16(pa, vb, oa[d], 0, 0, 0);
            }
        }

        #pragma unroll
        for (int d = 0; d < 4; ++d)
            #pragma unroll
            for (int r = 0; r < 4; ++r) {
                int q = q0 + lg * 4 + r;
                if (q < SEQ)
                    o[((long)(b * SEQ + q)) * DMODEL + h * 64 + d * 16 + lr] =
                        __float2bfloat16(oa[d][r]);
            }
    }
}

// ---------------------------------------------------------------- final proj
__global__ __launch_bounds__(256) void proj_kernel(
    const float* __restrict__ cls_ln,  // [32,768]
    const float* __restrict__ proj,    // [768,512]
    float* __restrict__ out)           // [32,512]
{
    int idx = blockIdx.x * 256 + threadIdx.x;
    int m = idx >> 9, n = idx & 511;
    float s = 0.f;
    #pragma unroll 8
    for (int k = 0; k < 768; ++k)
        s += cls_ln[m * 768 + k] * proj[k * 512 + n];
    out[idx] = s;
}

// ---------------------------------------------------------------- launcher
extern "C" void kernel_launch(void* const* d_in, const int* in_sizes, int n_in,
                              void* d_out, int out_size, void* d_ws, size_t ws_size,
                              hipStream_t stream) {
    const float* x_inp    = (const float*)d_in[0];
    const float* conv_w   = (const float*)d_in[1];
    const float* cls_emb  = (const float*)d_in[2];
    const float* pos_emb  = (const float*)d_in[3];
    const float* ln_pre_w = (const float*)d_in[4];
    const float* ln_pre_b = (const float*)d_in[5];
    const float* ln1_w    = (const float*)d_in[6];
    const float* ln1_b    = (const float*)d_in[7];
    const float* qkv_w    = (const float*)d_in[8];
    const float* qkv_b    = (const float*)d_in[9];
    const float* out_w    = (const float*)d_in[10];
    const float* out_b    = (const float*)d_in[11];
    const float* ln2_w    = (const float*)d_in[12];
    const float* ln2_b    = (const float*)d_in[13];
    const float* fc1_w    = (const float*)d_in[14];
    const float* fc1_b    = (const float*)d_in[15];
    const float* fc2_w    = (const float*)d_in[16];
    const float* fc2_b    = (const float*)d_in[17];
    const float* ln_post_w= (const float*)d_in[18];
    const float* ln_post_b= (const float*)d_in[19];
    const float* proj     = (const float*)d_in[20];

    char* w = (char*)d_ws;
    __hip_bfloat16* wqkv = (__hip_bfloat16*)w; w += (size_t)LAYERS * 2304 * DMODEL * 2;
    __hip_bfloat16* wout = (__hip_bfloat16*)w; w += (size_t)LAYERS * DMODEL * DMODEL * 2;
    __hip_bfloat16* wfc1 = (__hip_bfloat16*)w; w += (size_t)LAYERS * FFDIM * DMODEL * 2;
    __hip_bfloat16* wfc2 = (__hip_bfloat16*)w; w += (size_t)LAYERS * DMODEL * FFDIM * 2;
    __hip_bfloat16* wconv= (__hip_bfloat16*)w; w += (size_t)DMODEL * DMODEL * 2;
    float* x             = (float*)w;          w += (size_t)MROWS * DMODEL * 4;
    __hip_bfloat16* y    = (__hip_bfloat16*)w; w += (size_t)MPAD * DMODEL * 2;
    __hip_bfloat16* qkvb = (__hip_bfloat16*)w; w += (size_t)MPAD * 2304 * 2;
    __hip_bfloat16* attno= (__hip_bfloat16*)w; w += (size_t)MPAD * DMODEL * 2;
    __hip_bfloat16* h1   = (__hip_bfloat16*)w; w += (size_t)MPAD * FFDIM * 2;
    __hip_bfloat16* patches = (__hip_bfloat16*)w; w += (size_t)NPATCH * BATCH * DMODEL * 2;
    float* clsb          = (float*)w;          w += (size_t)BATCH * DMODEL * 4;

    cvt_bf16_kernel<<<2048, 256, 0, stream>>>(qkv_w, wqkv, (long)LAYERS * 2304 * DMODEL);
    cvt_bf16_kernel<<<2048, 256, 0, stream>>>(out_w, wout, (long)LAYERS * DMODEL * DMODEL);
    cvt_bf16_kernel<<<2048, 256, 0, stream>>>(fc1_w, wfc1, (long)LAYERS * FFDIM * DMODEL);
    cvt_bf16_kernel<<<2048, 256, 0, stream>>>(fc2_w, wfc2, (long)LAYERS * DMODEL * FFDIM);
    cvt_bf16_kernel<<<512, 256, 0, stream>>>(conv_w, wconv, (long)DMODEL * DMODEL);

    im2col_kernel<<<NPATCH * BATCH, 256, 0, stream>>>(x_inp, patches);
    gemm_bf16<M_PATCH><<<49 * 6, 256, 0, stream>>>(
        patches, wconv, nullptr, x, nullptr, NPATCH * BATCH, DMODEL, DMODEL, 6, pos_emb);
    cls_token_kernel<<<BATCH, 256, 0, stream>>>(cls_emb, pos_emb, x);
    ln_kernel<0><<<MROWS, 256, 0, stream>>>(x, x, ln_pre_w, ln_pre_b, DMODEL, DMODEL);

    for (int l = 0; l < LAYERS; ++l) {
        ln_kernel<1><<<MROWS, 256, 0, stream>>>(x, y, ln1_w + l * DMODEL, ln1_b + l * DMODEL,
                                                DMODEL, DMODEL);
        gemm_bf16<M_QKVB><<<50 * 18, 256, 0, stream>>>(
            y, wqkv + (long)l * 2304 * DMODEL, qkv_b + (long)l * 2304, nullptr, qkvb,
            MROWS, 2304, DMODEL, 18, nullptr);
        attn_kernel<<<BATCH * NHEADS, 256, 0, stream>>>(qkvb, attno);
        gemm_bf16<M_ACC><<<50 * 6, 256, 0, stream>>>(
            attno, wout + (long)l * DMODEL * DMODEL, out_b + (long)l * DMODEL, x, nullptr,
            MROWS, DMODEL, DMODEL, 6, nullptr);
        ln_kernel<1><<<MROWS, 256, 0, stream>>>(x, y, ln2_w + l * DMODEL, ln2_b + l * DMODEL,
                                                DMODEL, DMODEL);
        gemm_bf16<M_GELU><<<50 * 24, 256, 0, stream>>>(
            y, wfc1 + (long)l * FFDIM * DMODEL, fc1_b + (long)l * FFDIM, nullptr, h1,
            MROWS, FFDIM, DMODEL, 24, nullptr);
        gemm_bf16<M_ACC><<<50 * 6, 256, 0, stream>>>(
            h1, wfc2 + (long)l * DMODEL * FFDIM, fc2_b + (long)l * DMODEL, x, nullptr,
            MROWS, DMODEL, FFDIM, 6, nullptr);
    }

    ln_kernel<0><<<BATCH, 256, 0, stream>>>(x, clsb, ln_post_w, ln_post_b,
                                            (long)SEQ * DMODEL, DMODEL);
    proj_kernel<<<(BATCH * OUTD) / 256, 256, 0, stream>>>(clsb, proj, (float*)d_out);
}

// Round 11
// 3504.846 us; speedup vs baseline: 1.4080x; 1.0246x over previous
//
#include <hip/hip_runtime.h>
#include <hip/hip_bf16.h>

// CLIP ViT-B/16 visual forward — Round 10: 8-phase-style 256x256 BK=64 GEMM
// (8 waves, counted vmcnt, raw s_barrier, setprio) for qkv/fc1; R8-proven
// 64x128 BK=64 2-phase GEMM for fc2/out/patch. Attention/LN unchanged.

#define LAYERS 12
#define DMODEL 768
#define NHEADS 12
#define DHEAD  64
#define FFDIM  3072
#define BATCH  32
#define SEQ    197
#define NPATCH 196
#define OUTD   512
#define MROWS  (BATCH * SEQ)   // 6304
#define MPAD   6400
#define SPAD   208
#define VSTR   208

typedef __attribute__((ext_vector_type(4))) float f32x4;
typedef __attribute__((ext_vector_type(8))) short bf16x8;

enum { M_F32 = 0, M_ACC = 1, M_GELU = 2, M_PATCH = 3, M_QKVB = 4 };

__device__ __forceinline__ float b2f(short s) {
    unsigned u = ((unsigned)(unsigned short)s) << 16;
    return __builtin_bit_cast(float, u);
}
__device__ __forceinline__ short f2b(float f) {
    __hip_bfloat16 h = __float2bfloat16(f);
    return __builtin_bit_cast(short, h);
}

__device__ __forceinline__ void gl2lds16(const void* g, void* l) {
    __builtin_amdgcn_global_load_lds(
        (const __attribute__((address_space(1))) void*)g,
        (__attribute__((address_space(3))) void*)l, 16, 0, 0);
}

__device__ __forceinline__ void hard_barrier() {
    asm volatile("" ::: "memory");
    __builtin_amdgcn_s_barrier();
    asm volatile("" ::: "memory");
}

// ---------------------------------------------------------------- weight cvt
__global__ __launch_bounds__(256) void cvt_bf16_kernel(
    const float* __restrict__ src, __hip_bfloat16* __restrict__ dst, long n)
{
    long i0 = ((long)blockIdx.x * 256 + threadIdx.x) * 4;
    long stride = (long)gridDim.x * 1024;
    for (long i = i0; i < n; i += stride) {
        float4 v = *reinterpret_cast<const float4*>(&src[i]);
        dst[i + 0] = __float2bfloat16(v.x);
        dst[i + 1] = __float2bfloat16(v.y);
        dst[i + 2] = __float2bfloat16(v.z);
        dst[i + 3] = __float2bfloat16(v.w);
    }
}

// ---------------------------------------------------------------- im2col
__global__ __launch_bounds__(256) void im2col_kernel(
    const float* __restrict__ x_inp, __hip_bfloat16* __restrict__ patches)
{
    int bp = blockIdx.x;
    int b = bp / NPATCH, p = bp % NPATCH;
    int py = p / 14, px = p % 14;
    const float* xb = x_inp + (long)b * 3 * 224 * 224;
    for (int e = threadIdx.x; e < 768; e += 256) {
        int c = e >> 8, i = (e >> 4) & 15, j = e & 15;
        patches[(long)bp * 768 + e] =
            __float2bfloat16(xb[((long)c * 224 + py * 16 + i) * 224 + px * 16 + j]);
    }
}

__global__ __launch_bounds__(256) void cls_token_kernel(
    const float* __restrict__ cls_emb, const float* __restrict__ pos_emb,
    float* __restrict__ x)
{
    int b = blockIdx.x;
    for (int d = threadIdx.x; d < DMODEL; d += 256)
        x[(long)b * SEQ * DMODEL + d] = cls_emb[d] + pos_emb[d];
}

// ---------------------------------------------------------------- layernorm
template<int OB>
__global__ __launch_bounds__(256) void ln_kernel(
    const float* __restrict__ in, void* __restrict__ out,
    const float* __restrict__ w, const float* __restrict__ bb,
    long in_stride, long out_stride)
{
    int row = blockIdx.x;
    const float* xr = in + (long)row * in_stride;
    int t = threadIdx.x;
    int lane = t & 63, wid = t >> 6;
    __shared__ float red[8];

    float v[3];
    float s = 0.f;
    #pragma unroll
    for (int i = 0; i < 3; ++i) { v[i] = xr[t + i * 256]; s += v[i]; }
    #pragma unroll
    for (int off = 32; off; off >>= 1) s += __shfl_xor(s, off);
    if (lane == 0) red[wid] = s;
    __syncthreads();
    float mean = (red[0] + red[1] + red[2] + red[3]) * (1.0f / DMODEL);
    float sq = 0.f;
    #pragma unroll
    for (int i = 0; i < 3; ++i) { float d = v[i] - mean; sq += d * d; }
    #pragma unroll
    for (int off = 32; off; off >>= 1) sq += __shfl_xor(sq, off);
    if (lane == 0) red[4 + wid] = sq;
    __syncthreads();
    float rstd = rsqrtf((red[4] + red[5] + red[6] + red[7]) * (1.0f / DMODEL) + 1e-5f);
    #pragma unroll
    for (int i = 0; i < 3; ++i) {
        int d = t + i * 256;
        float o = (v[i] - mean) * rstd * w[d] + bb[d];
        if (OB) ((__hip_bfloat16*)out)[(long)row * out_stride + d] = __float2bfloat16(o);
        else    ((float*)out)[(long)row * out_stride + d] = o;
    }
}

// ---------------------------------------------------------------- small GEMM
// R8-proven: 64x128 tile, BK=64, 2-buffer 48KB, chunk^=row&7 swizzle.
template<int MODE>
__global__ __launch_bounds__(256) void gemm_bf16(
    const __hip_bfloat16* __restrict__ A, const __hip_bfloat16* __restrict__ W,
    const float* __restrict__ bias, float* __restrict__ Cf,
    __hip_bfloat16* __restrict__ Cb, int M, int N, int K, int NB,
    const float* __restrict__ pos)
{
    __shared__ short As[2][64 * 64];
    __shared__ short Bs[2][128 * 64];
    int tid = threadIdx.x, lane = tid & 63, wv = tid >> 6;

    int nwg = gridDim.x, bid = blockIdx.x;
    int qq = nwg >> 3, rr = nwg & 7;
    int xcd = bid & 7, idx = bid >> 3;
    int newid = (xcd < rr ? xcd * (qq + 1) : rr * (qq + 1) + (xcd - rr) * qq) + idx;

    int bm = (newid / NB) * 64, bn = (newid % NB) * 128;
    int wn = wv * 32;
    f32x4 acc[4][2] = {};

    int sr = tid >> 3, sc = tid & 7;
    int c_log = sc ^ (sr & 7);
    const short* Ag = (const short*)A + (long)(bm + sr) * K + (c_log << 3);
    const short* Bg = (const short*)W + (long)(bn + sr) * K + (c_log << 3);
    const long K32 = (long)32 * K;

    int lg = lane >> 4, lr16 = lane & 15;
    int aoff[2][4], boff[2][2];
    #pragma unroll
    for (int s = 0; s < 2; ++s) {
        #pragma unroll
        for (int i = 0; i < 4; ++i) {
            int ra = i * 16 + lr16;
            aoff[s][i] = (ra << 6) + ((((s << 2) | lg) ^ (ra & 7)) << 3);
        }
        #pragma unroll
        for (int j = 0; j < 2; ++j) {
            int rb = wn + j * 16 + lr16;
            boff[s][j] = (rb << 6) + ((((s << 2) | lg) ^ (rb & 7)) << 3);
        }
    }

    const int KT = K >> 6;
    {
        char* Ad = (char*)&As[0][0]; char* Bd = (char*)&Bs[0][0];
        gl2lds16(Ag,           Ad + tid * 16);
        gl2lds16(Ag + K32,     Ad + 4096 + tid * 16);
        gl2lds16(Bg,           Bd + tid * 16);
        gl2lds16(Bg + K32,     Bd + 4096 + tid * 16);
        gl2lds16(Bg + 2 * K32, Bd + 8192 + tid * 16);
        gl2lds16(Bg + 3 * K32, Bd + 12288 + tid * 16);
    }
    __syncthreads();

    for (int t = 0; t < KT; ++t) {
        if (t + 1 < KT) {
            int ktn = (t + 1) << 6;
            char* Ad = (char*)&As[(t & 1) ^ 1][0];
            char* Bd = (char*)&Bs[(t & 1) ^ 1][0];
            gl2lds16(Ag + ktn,           Ad + tid * 16);
            gl2lds16(Ag + K32 + ktn,     Ad + 4096 + tid * 16);
            gl2lds16(Bg + ktn,           Bd + tid * 16);
            gl2lds16(Bg + K32 + ktn,     Bd + 4096 + tid * 16);
            gl2lds16(Bg + 2 * K32 + ktn, Bd + 8192 + tid * 16);
            gl2lds16(Bg + 3 * K32 + ktn, Bd + 12288 + tid * 16);
        }
        const short* Ab = &As[t & 1][0];
        const short* Bb = &Bs[t & 1][0];
        #pragma unroll
        for (int s = 0; s < 2; ++s) {
            bf16x8 af[4], bfr[2];
            #pragma unroll
            for (int i = 0; i < 4; ++i)
                af[i] = *reinterpret_cast<const bf16x8*>(&Ab[aoff[s][i]]);
            #pragma unroll
            for (int j = 0; j < 2; ++j)
                bfr[j] = *reinterpret_cast<const bf16x8*>(&Bb[boff[s][j]]);
            #pragma unroll
            for (int mi = 0; mi < 4; ++mi)
                #pragma unroll
                for (int ni = 0; ni < 2; ++ni)
                    acc[mi][ni] = __builtin_amdgcn_mfma_f32_16x16x32_bf16(
                        af[mi], bfr[ni], acc[mi][ni], 0, 0, 0);
        }
        __syncthreads();
    }

    #pragma unroll
    for (int mi = 0; mi < 4; ++mi) {
        int row0 = bm + mi * 16 + (lane >> 4) * 4;
        #pragma unroll
        for (int ni = 0; ni < 2; ++ni) {
            int col = bn + wn + ni * 16 + lr16;
            #pragma unroll
            for (int r = 0; r < 4; ++r) {
                int row = row0 + r;
                if (row >= M) continue;
                float v = acc[mi][ni][r];
                if (MODE == M_PATCH) {
                    int pb = row / 196, pp = row - pb * 196;
                    Cf[((long)(pb * SEQ + 1 + pp)) * DMODEL + col] =
                        v + pos[(long)(1 + pp) * DMODEL + col];
                } else {
                    v += bias[col];
                    long idx2 = (long)row * N + col;
                    if (MODE == M_F32)      Cf[idx2] = v;
                    else if (MODE == M_ACC) Cf[idx2] += v;
                    else if (MODE == M_QKVB) Cb[idx2] = __float2bfloat16(v);
                    else if (MODE == M_GELU)
                        Cb[idx2] = __float2bfloat16(v / (1.f + __expf(-1.702f * v)));
                }
            }
        }
    }
}

// ---------------------------------------------------------------- big GEMM
// 256x256 tile, BK=64, 8 waves (2M x 4N), per-wave 128x64 (8x4 frags).
// 4 phases per K-tile: {stage 2x gl2lds ; 8x ds_read ; s_barrier ;
// lgkmcnt(0)+sched_barrier ; setprio(1) 16 MFMA setprio(0) ; s_barrier}.
// Counted vmcnt(2) once per tile (phase 4); never 0 in steady state.
// LDS 128KB: A[2][256][64] + B[2][256][64], chunk^=row&7 swizzle.
// Unit u = rows u*64..u*64+63 (8KB = 1 gl2lds/thread). Rotation:
//   c.ph1 stages (c+1).A u1,u3 ; ph2 (c+1).B u0,u1 ; ph3 (c+1).B u2,u3 ;
//   ph4 (c+2).A u0,u2  (A u0/u2 are mh0 rows: last read at c.ph2 -> safe).
template<int MODE>
__global__ __launch_bounds__(512) void gemm_big(
    const __hip_bfloat16* __restrict__ A, const __hip_bfloat16* __restrict__ W,
    const float* __restrict__ bias, __hip_bfloat16* __restrict__ Cb,
    int M, int N, int K, int NB)
{
    __shared__ __align__(16) char smem[131072];
    int tid = threadIdx.x, lane = tid & 63, wv = tid >> 6;

    int nwg = gridDim.x, bid = blockIdx.x;
    int qq = nwg >> 3, rr = nwg & 7;
    int xcd = bid & 7, idx = bid >> 3;
    int newid = (xcd < rr ? xcd * (qq + 1) : rr * (qq + 1) + (xcd - rr) * qq) + idx;

    int bm = (newid / NB) * 256, bn = (newid % NB) * 256;
    int wr = wv >> 2, wc = wv & 3;
    f32x4 acc[8][4] = {};

    // staging: thread t -> (row within unit = t/8, chunk slot = t%8)
    int sr = tid >> 3, scn = tid & 7;
    int c_log = scn ^ (sr & 7);
    const short* Aga = (const short*)A + (long)(bm + sr) * K + (c_log << 3);
    const short* Bga = (const short*)W + (long)(bn + sr) * K + (c_log << 3);
    const long U = (long)64 * K;   // one unit = 64 rows

    int lg = lane >> 4, lr16 = lane & 15;
    int aoff[2][2][4], boff[2][4];
    #pragma unroll
    for (int ks = 0; ks < 2; ++ks) {
        int kc = (ks << 2) | lg;
        #pragma unroll
        for (int mh = 0; mh < 2; ++mh)
            #pragma unroll
            for (int i = 0; i < 4; ++i) {
                int ra = wr * 128 + mh * 64 + i * 16 + lr16;
                aoff[mh][ks][i] = (ra << 6) + ((kc ^ (ra & 7)) << 3);
            }
        #pragma unroll
        for (int j = 0; j < 4; ++j) {
            int rb = wc * 64 + j * 16 + lr16;
            boff[ks][j] = (rb << 6) + ((kc ^ (rb & 7)) << 3);
        }
    }

    const int KT = K >> 6;

#define GB_STAGE_A(BUF, u, kt) gl2lds16(Aga + (long)(u) * U + (kt), (BUF) + (u) * 8192 + tid * 16)
#define GB_STAGE_B(BUF, u, kt) gl2lds16(Bga + (long)(u) * U + (kt), (BUF) + (u) * 8192 + tid * 16)

    // prologue: tile0 full + tile1 units 0,2 of A
    {
        char* A0 = smem, *B0 = smem + 65536;
        GB_STAGE_A(A0, 0, 0); GB_STAGE_A(A0, 1, 0);
        GB_STAGE_A(A0, 2, 0); GB_STAGE_A(A0, 3, 0);
        GB_STAGE_B(B0, 0, 0); GB_STAGE_B(B0, 1, 0);
        GB_STAGE_B(B0, 2, 0); GB_STAGE_B(B0, 3, 0);
        if (KT > 1) {
            char* A1 = smem + 32768;
            GB_STAGE_A(A1, 0, 64); GB_STAGE_A(A1, 2, 64);
            asm volatile("s_waitcnt vmcnt(2)" ::: "memory");
        } else {
            asm volatile("s_waitcnt vmcnt(0)" ::: "memory");
        }
        hard_barrier();
    }

#define GB_PHASE(MH, KS)                                                        \
    {                                                                           \
        bf16x8 af[4], bfv[4];                                                   \
        _Pragma("unroll")                                                       \
        for (int i = 0; i < 4; ++i) {                                           \
            af[i]  = *reinterpret_cast<const bf16x8*>(&Ab_[aoff[MH][KS][i]]);   \
            bfv[i] = *reinterpret_cast<const bf16x8*>(&Bb_[boff[KS][i]]);       \
        }                                                                       \
        hard_barrier();                                                         \
        asm volatile("s_waitcnt lgkmcnt(0)" ::: "memory");                      \
        __builtin_amdgcn_sched_barrier(0);                                      \
        __builtin_amdgcn_s_setprio(1);                                          \
        _Pragma("unroll")                                                       \
        for (int i = 0; i < 4; ++i)                                             \
            _Pragma("unroll")                                                   \
            for (int j = 0; j < 4; ++j)                                         \
                acc[(MH) * 4 + i][j] = __builtin_amdgcn_mfma_f32_16x16x32_bf16( \
                    af[i], bfv[j], acc[(MH) * 4 + i][j], 0, 0, 0);              \
        __builtin_amdgcn_s_setprio(0);                                          \
    }

    for (int c = 0; c < KT; ++c) {
        const int d = c & 1, d1 = d ^ 1;
        const short* Ab_ = (const short*)(smem + d * 32768);
        const short* Bb_ = (const short*)(smem + 65536 + d * 32768);
        char* An = smem + d1 * 32768;
        char* Bn = smem + 65536 + d1 * 32768;
        char* Ad2 = smem + d * 32768;          // (c+2) shares dbuf with c
        const int kt1 = (c + 1) << 6, kt2 = (c + 2) << 6;
        const bool h1 = (c + 1 < KT), h2 = (c + 2 < KT);

        // phase 1 (mh0,ks0): stage (c+1).A units 1,3
        if (h1) { GB_STAGE_A(An, 1, kt1); GB_STAGE_A(An, 3, kt1); }
        GB_PHASE(0, 0);
        hard_barrier();

        // phase 2 (mh0,ks1): stage (c+1).B units 0,1
        if (h1) { GB_STAGE_B(Bn, 0, kt1); GB_STAGE_B(Bn, 1, kt1); }
        GB_PHASE(0, 1);
        hard_barrier();

        // phase 3 (mh1,ks0): stage (c+1).B units 2,3
        if (h1) { GB_STAGE_B(Bn, 2, kt1); GB_STAGE_B(Bn, 3, kt1); }
        GB_PHASE(1, 0);
        hard_barrier();

        // phase 4 (mh1,ks1): stage (c+2).A units 0,2 (mh0 rows, free since ph2)
        if (h2) { GB_STAGE_A(Ad2, 0, kt2); GB_STAGE_A(Ad2, 2, kt2); }
        GB_PHASE(1, 1);
        if (h2) asm volatile("s_waitcnt vmcnt(2)" ::: "memory");
        else    asm volatile("s_waitcnt vmcnt(0)" ::: "memory");
        hard_barrier();
    }

    #pragma unroll
    for (int mi = 0; mi < 8; ++mi) {
        int row0 = bm + wr * 128 + (mi >> 2) * 64 + (mi & 3) * 16 + lg * 4;
        #pragma unroll
        for (int ni = 0; ni < 4; ++ni) {
            int col = bn + wc * 64 + ni * 16 + lr16;
            #pragma unroll
            for (int r = 0; r < 4; ++r) {
                int row = row0 + r;
                if (row >= M) continue;
                float v = acc[mi][ni][r] + bias[col];
                long idx2 = (long)row * N + col;
                if (MODE == M_QKVB) Cb[idx2] = __float2bfloat16(v);
                else                Cb[idx2] = __float2bfloat16(v / (1.f + __expf(-1.702f * v)));
            }
        }
    }
#undef GB_PHASE
#undef GB_STAGE_A
#undef GB_STAGE_B
}

// ---------------------------------------------------------------- attention
__global__ __launch_bounds__(256) void attn_kernel(
    const __hip_bfloat16* __restrict__ qkv, __hip_bfloat16* __restrict__ o)
{
    int bh = blockIdx.x;
    int b = bh / NHEADS, h = bh % NHEADS;
    int tid = threadIdx.x, lane = tid & 63, wv = tid >> 6;
    __shared__ short Ks[SPAD * 64];
    __shared__ short Vt[64 * VSTR];
    __shared__ short Ps[4][16 * VSTR];
    const short* base = (const short*)qkv + (long)b * SEQ * 2304;

    for (int idx = tid; idx < SPAD * 8; idx += 256) {
        int r = idx >> 3, c = idx & 7;
        int4 val = make_int4(0, 0, 0, 0);
        if (r < SEQ)
            val = *reinterpret_cast<const int4*>(base + (long)r * 2304 + 768 + h * 64 + c * 8);
        *reinterpret_cast<int4*>(&Ks[r * 64 + ((c ^ (r & 7)) << 3)]) = val;
    }
    for (int idx = tid; idx < SPAD * 64; idx += 256) {
        int k = idx >> 6, d = idx & 63;
        short v = (k < SEQ) ? base[(long)k * 2304 + 1536 + h * 64 + d] : (short)0;
        Vt[d * VSTR + k] = v;
    }
    __syncthreads();

    int lg = lane >> 4, lr = lane & 15;
    short* Pw = Ps[wv];

    for (int ch = wv; ch < 13; ch += 4) {
        int q0 = ch * 16;
        const short* qp = (const short*)qkv +
            ((long)(b * SEQ) + q0 + lr) * 2304 + h * 64 + (lg << 3);
        bf16x8 qa = *reinterpret_cast<const bf16x8*>(qp);
        bf16x8 qb = *reinterpret_cast<const bf16x8*>(qp + 32);

        f32x4 sc[13];
        #pragma unroll
        for (int f = 0; f < 13; ++f) sc[f] = (f32x4){0.f, 0.f, 0.f, 0.f};
        #pragma unroll
        for (int f = 0; f < 13; ++f) {
            int row = f * 16 + lr;
            int sw = row & 7;
            const short* kr = &Ks[row * 64];
            bf16x8 k0 = *reinterpret_cast<const bf16x8*>(&kr[((lg + 0) ^ sw) << 3]);
            bf16x8 k1 = *reinterpret_cast<const bf16x8*>(&kr[((lg + 4) ^ sw) << 3]);
            sc[f] = __builtin_amdgcn_mfma_f32_16x16x32_bf16(qa, k0, sc[f], 0, 0, 0);
            sc[f] = __builtin_amdgcn_mfma_f32_16x16x32_bf16(qb, k1, sc[f], 0, 0, 0);
        }

        float mrow[4] = {-1e30f, -1e30f, -1e30f, -1e30f};
        #pragma unroll
        for (int f = 0; f < 13; ++f) {
            bool ok = f * 16 + lr < SEQ;
            #pragma unroll
            for (int r = 0; r < 4; ++r)
                if (ok) mrow[r] = fmaxf(mrow[r], sc[f][r] * 0.125f);
        }
        #pragma unroll
        for (int r = 0; r < 4; ++r)
            #pragma unroll
            for (int off = 8; off; off >>= 1)
                mrow[r] = fmaxf(mrow[r], __shfl_xor(mrow[r], off));
        float esum[4] = {0.f, 0.f, 0.f, 0.f};
        #pragma unroll
        for (int f = 0; f < 13; ++f) {
            bool ok = f * 16 + lr < SEQ;
            #pragma unroll
            for (int r = 0; r < 4; ++r) {
                float e = ok ? __expf(sc[f][r] * 0.125f - mrow[r]) : 0.f;
                sc[f][r] = e;
                esum[r] += e;
            }
        }
        #pragma unroll
        for (int r = 0; r < 4; ++r)
            #pragma unroll
            for (int off = 8; off; off >>= 1)
                esum[r] += __shfl_xor(esum[r], off);
        float inv[4];
        #pragma unroll
        for (int r = 0; r < 4; ++r) inv[r] = 1.0f / esum[r];

        #pragma unroll
        for (int f = 0; f < 13; ++f)
            #pragma unroll
            for (int r = 0; r < 4; ++r)
                Pw[(lg * 4 + r) * VSTR + f * 16 + lr] = f2b(sc[f][r] * inv[r]);

        f32x4 oa[4] = {};
        #pragma unroll
        for (int ks = 0; ks < 7; ++ks) {
            int kb = ks * 32 + (lg << 3);
            bf16x8 pa = {};
            if (kb < SPAD) pa = *reinterpret_cast<const bf16x8*>(&Pw[lr * VSTR + kb]);
            #pragma unroll
            for (int d = 0; d < 4; ++d) {
                bf16x8 vb = {};
                if (kb < SPAD)
                    vb = *reinterpret_cast<const bf16x8*>(&Vt[(d * 16 + lr) * VSTR + kb]);
                oa[d] = __builtin_amdgcn_mfma_f32_16x16x32_bf16(pa, vb, oa[d], 0, 0, 0);
            }
        }

        #pragma unroll
        for (int d = 0; d < 4; ++d)
            #pragma unroll
            for (int r = 0; r < 4; ++r) {
                int q = q0 + lg * 4 + r;
                if (q < SEQ)
                    o[((long)(b * SEQ + q)) * DMODEL + h * 64 + d * 16 + lr] =
                        __float2bfloat16(oa[d][r]);
            }
    }
}

// ---------------------------------------------------------------- final proj
__global__ __launch_bounds__(256) void proj_kernel(
    const float* __restrict__ cls_ln, const float* __restrict__ proj,
    float* __restrict__ out)
{
    int idx = blockIdx.x * 256 + threadIdx.x;
    int m = idx >> 9, n = idx & 511;
    float s = 0.f;
    #pragma unroll 8
    for (int k = 0; k < 768; ++k)
        s += cls_ln[m * 768 + k] * proj[k * 512 + n];
    out[idx] = s;
}

// ---------------------------------------------------------------- launcher
extern "C" void kernel_launch(void* const* d_in, const int* in_sizes, int n_in,
                              void* d_out, int out_size, void* d_ws, size_t ws_size,
                              hipStream_t stream) {
    const float* x_inp    = (const float*)d_in[0];
    const float* conv_w   = (const float*)d_in[1];
    const float* cls_emb  = (const float*)d_in[2];
    const float* pos_emb  = (const float*)d_in[3];
    const float* ln_pre_w = (const float*)d_in[4];
    const float* ln_pre_b = (const float*)d_in[5];
    const float* ln1_w    = (const float*)d_in[6];
    const float* ln1_b    = (const float*)d_in[7];
    const float* qkv_w    = (const float*)d_in[8];
    const float* qkv_b    = (const float*)d_in[9];
    const float* out_w    = (const float*)d_in[10];
    const float* out_b    = (const float*)d_in[11];
    const float* ln2_w    = (const float*)d_in[12];
    const float* ln2_b    = (const float*)d_in[13];
    const float* fc1_w    = (const float*)d_in[14];
    const float* fc1_b    = (const float*)d_in[15];
    const float* fc2_w    = (const float*)d_in[16];
    const float* fc2_b    = (const float*)d_in[17];
    const float* ln_post_w= (const float*)d_in[18];
    const float* ln_post_b= (const float*)d_in[19];
    const float* proj     = (const float*)d_in[20];

    char* w = (char*)d_ws;
    __hip_bfloat16* wqkv = (__hip_bfloat16*)w; w += (size_t)LAYERS * 2304 * DMODEL * 2;
    __hip_bfloat16* wout = (__hip_bfloat16*)w; w += (size_t)LAYERS * DMODEL * DMODEL * 2;
    __hip_bfloat16* wfc1 = (__hip_bfloat16*)w; w += (size_t)LAYERS * FFDIM * DMODEL * 2;
    __hip_bfloat16* wfc2 = (__hip_bfloat16*)w; w += (size_t)LAYERS * DMODEL * FFDIM * 2;
    __hip_bfloat16* wconv= (__hip_bfloat16*)w; w += (size_t)DMODEL * DMODEL * 2;
    float* x             = (float*)w;          w += (size_t)MROWS * DMODEL * 4;
    __hip_bfloat16* y    = (__hip_bfloat16*)w; w += (size_t)MPAD * DMODEL * 2;
    __hip_bfloat16* qkvb = (__hip_bfloat16*)w; w += (size_t)MPAD * 2304 * 2;
    __hip_bfloat16* attno= (__hip_bfloat16*)w; w += (size_t)MPAD * DMODEL * 2;
    __hip_bfloat16* h1   = (__hip_bfloat16*)w; w += (size_t)MPAD * FFDIM * 2;
    __hip_bfloat16* patches = (__hip_bfloat16*)w; w += (size_t)NPATCH * BATCH * DMODEL * 2;
    float* clsb          = (float*)w;          w += (size_t)BATCH * DMODEL * 4;

    cvt_bf16_kernel<<<2048, 256, 0, stream>>>(qkv_w, wqkv, (long)LAYERS * 2304 * DMODEL);
    cvt_bf16_kernel<<<2048, 256, 0, stream>>>(out_w, wout, (long)LAYERS * DMODEL * DMODEL);
    cvt_bf16_kernel<<<2048, 256, 0, stream>>>(fc1_w, wfc1, (long)LAYERS * FFDIM * DMODEL);
    cvt_bf16_kernel<<<2048, 256, 0, stream>>>(fc2_w, wfc2, (long)LAYERS * DMODEL * FFDIM);
    cvt_bf16_kernel<<<512, 256, 0, stream>>>(conv_w, wconv, (long)DMODEL * DMODEL);

    im2col_kernel<<<NPATCH * BATCH, 256, 0, stream>>>(x_inp, patches);
    gemm_bf16<M_PATCH><<<98 * 6, 256, 0, stream>>>(
        patches, wconv, nullptr, x, nullptr, NPATCH * BATCH, DMODEL, DMODEL, 6, pos_emb);
    cls_token_kernel<<<BATCH, 256, 0, stream>>>(cls_emb, pos_emb, x);
    ln_kernel<0><<<MROWS, 256, 0, stream>>>(x, x, ln_pre_w, ln_pre_b, DMODEL, DMODEL);

    for (int l = 0; l < LAYERS; ++l) {
        ln_kernel<1><<<MROWS, 256, 0, stream>>>(x, y, ln1_w + l * DMODEL, ln1_b + l * DMODEL,
                                                DMODEL, DMODEL);
        gemm_big<M_QKVB><<<25 * 9, 512, 0, stream>>>(
            y, wqkv + (long)l * 2304 * DMODEL, qkv_b + (long)l * 2304, qkvb,
            MROWS, 2304, DMODEL, 9);
        attn_kernel<<<BATCH * NHEADS, 256, 0, stream>>>(qkvb, attno);
        gemm_bf16<M_ACC><<<99 * 6, 256, 0, stream>>>(
            attno, wout + (long)l * DMODEL * DMODEL, out_b + (long)l * DMODEL, x, nullptr,
            MROWS, DMODEL, DMODEL, 6, nullptr);
        ln_kernel<1><<<MROWS, 256, 0, stream>>>(x, y, ln2_w + l * DMODEL, ln2_b + l * DMODEL,
                                                DMODEL, DMODEL);
        gemm_big<M_GELU><<<25 * 12, 512, 0, stream>>>(
            y, wfc1 + (long)l * FFDIM * DMODEL, fc1_b + (long)l * FFDIM, h1,
            MROWS, FFDIM, DMODEL, 12);
        gemm_bf16<M_ACC><<<99 * 6, 256, 0, stream>>>(
            h1, wfc2 + (long)l * DMODEL * FFDIM, fc2_b + (long)l * DMODEL, x, nullptr,
            MROWS, DMODEL, FFDIM, 6, nullptr);
    }

    ln_kernel<0><<<BATCH, 256, 0, stream>>>(x, clsb, ln_post_w, ln_post_b,
                                            (long)SEQ * DMODEL, DMODEL);
    proj_kernel<<<(BATCH * OUTD) / 256, 256, 0, stream>>>(clsb, proj, (float*)d_out);
}

// Round 12
// 3403.572 us; speedup vs baseline: 1.4498x; 1.0298x over previous
//
#include <hip/hip_runtime.h>
#include <hip/hip_bf16.h>

// CLIP ViT-B/16 visual forward — Round 12: GEMM = exact R8 (best passing,
// 64x128 BK=64 2-phase, 48KB LDS). NEW: wave-per-row vectorized LayerNorm
// (float4 loads, shfl-only reduce, no LDS/barriers). Attention unchanged.

#define LAYERS 12
#define DMODEL 768
#define NHEADS 12
#define DHEAD  64
#define FFDIM  3072
#define BATCH  32
#define SEQ    197
#define NPATCH 196
#define OUTD   512
#define MROWS  (BATCH * SEQ)   // 6304
#define MPAD   6400
#define SPAD   208
#define VSTR   208

typedef __attribute__((ext_vector_type(4))) float f32x4;
typedef __attribute__((ext_vector_type(8))) short bf16x8;

enum { M_F32 = 0, M_ACC = 1, M_GELU = 2, M_PATCH = 3, M_QKVB = 4 };

__device__ __forceinline__ float b2f(short s) {
    unsigned u = ((unsigned)(unsigned short)s) << 16;
    return __builtin_bit_cast(float, u);
}
__device__ __forceinline__ short f2b(float f) {
    __hip_bfloat16 h = __float2bfloat16(f);
    return __builtin_bit_cast(short, h);
}
__device__ __forceinline__ unsigned short f2bu(float f) {
    __hip_bfloat16 h = __float2bfloat16(f);
    return __builtin_bit_cast(unsigned short, h);
}

__device__ __forceinline__ void gl2lds16(const void* g, void* l) {
    __builtin_amdgcn_global_load_lds(
        (const __attribute__((address_space(1))) void*)g,
        (__attribute__((address_space(3))) void*)l, 16, 0, 0);
}

// ---------------------------------------------------------------- weight cvt
__global__ __launch_bounds__(256) void cvt_bf16_kernel(
    const float* __restrict__ src, __hip_bfloat16* __restrict__ dst, long n)
{
    long i0 = ((long)blockIdx.x * 256 + threadIdx.x) * 4;
    long stride = (long)gridDim.x * 1024;
    for (long i = i0; i < n; i += stride) {
        float4 v = *reinterpret_cast<const float4*>(&src[i]);
        dst[i + 0] = __float2bfloat16(v.x);
        dst[i + 1] = __float2bfloat16(v.y);
        dst[i + 2] = __float2bfloat16(v.z);
        dst[i + 3] = __float2bfloat16(v.w);
    }
}

// ---------------------------------------------------------------- im2col
__global__ __launch_bounds__(256) void im2col_kernel(
    const float* __restrict__ x_inp, __hip_bfloat16* __restrict__ patches)
{
    int bp = blockIdx.x;
    int b = bp / NPATCH, p = bp % NPATCH;
    int py = p / 14, px = p % 14;
    const float* xb = x_inp + (long)b * 3 * 224 * 224;
    for (int e = threadIdx.x; e < 768; e += 256) {
        int c = e >> 8, i = (e >> 4) & 15, j = e & 15;
        patches[(long)bp * 768 + e] =
            __float2bfloat16(xb[((long)c * 224 + py * 16 + i) * 224 + px * 16 + j]);
    }
}

__global__ __launch_bounds__(256) void cls_token_kernel(
    const float* __restrict__ cls_emb, const float* __restrict__ pos_emb,
    float* __restrict__ x)
{
    int b = blockIdx.x;
    for (int d = threadIdx.x; d < DMODEL; d += 256)
        x[(long)b * SEQ * DMODEL + d] = cls_emb[d] + pos_emb[d];
}

// ---------------------------------------------------------------- layernorm
// one WAVE per row; 4 rows per 256-thread block. float4 loads (lane*16B
// coalesced), shfl_xor reduce, no LDS, no barriers. OB=1 -> bf16 out.
template<int OB>
__global__ __launch_bounds__(256) void ln_kernel(
    const float* __restrict__ in, void* __restrict__ out,
    const float* __restrict__ w, const float* __restrict__ bb,
    long in_stride, long out_stride, int nrows)
{
    int row = blockIdx.x * 4 + (threadIdx.x >> 6);
    if (row >= nrows) return;
    int lane = threadIdx.x & 63;
    const float* xr = in + (long)row * in_stride;

    float4 v[3];
    float s = 0.f;
    #pragma unroll
    for (int i = 0; i < 3; ++i) {
        v[i] = *reinterpret_cast<const float4*>(&xr[i * 256 + lane * 4]);
        s += v[i].x + v[i].y + v[i].z + v[i].w;
    }
    #pragma unroll
    for (int off = 32; off; off >>= 1) s += __shfl_xor(s, off);
    float mean = s * (1.0f / DMODEL);
    float sq = 0.f;
    #pragma unroll
    for (int i = 0; i < 3; ++i) {
        float a = v[i].x - mean, b2 = v[i].y - mean,
              c = v[i].z - mean, d = v[i].w - mean;
        sq += a * a + b2 * b2 + c * c + d * d;
    }
    #pragma unroll
    for (int off = 32; off; off >>= 1) sq += __shfl_xor(sq, off);
    float rstd = rsqrtf(sq * (1.0f / DMODEL) + 1e-5f);

    #pragma unroll
    for (int i = 0; i < 3; ++i) {
        int d0 = i * 256 + lane * 4;
        float4 wv = *reinterpret_cast<const float4*>(&w[d0]);
        float4 bv = *reinterpret_cast<const float4*>(&bb[d0]);
        float o0 = (v[i].x - mean) * rstd * wv.x + bv.x;
        float o1 = (v[i].y - mean) * rstd * wv.y + bv.y;
        float o2 = (v[i].z - mean) * rstd * wv.z + bv.z;
        float o3 = (v[i].w - mean) * rstd * wv.w + bv.w;
        if (OB) {
            ushort4 u;
            u.x = f2bu(o0); u.y = f2bu(o1); u.z = f2bu(o2); u.w = f2bu(o3);
            *reinterpret_cast<ushort4*>(
                &((__hip_bfloat16*)out)[(long)row * out_stride + d0]) = u;
        } else {
            float4 o = make_float4(o0, o1, o2, o3);
            *reinterpret_cast<float4*>(&((float*)out)[(long)row * out_stride + d0]) = o;
        }
    }
}

// ---------------------------------------------------------------- bf16 GEMM
// R8-proven: 64x128 tile, BK=64, 2-buffer 48KB LDS, prefetch-next + one
// barrier per K-step, chunk^=row&7 swizzle, bijective XCD-chunked grid.
template<int MODE>
__global__ __launch_bounds__(256) void gemm_bf16(
    const __hip_bfloat16* __restrict__ A, const __hip_bfloat16* __restrict__ W,
    const float* __restrict__ bias, float* __restrict__ Cf,
    __hip_bfloat16* __restrict__ Cb, int M, int N, int K, int NB,
    const float* __restrict__ pos)
{
    __shared__ short As[2][64 * 64];
    __shared__ short Bs[2][128 * 64];
    int tid = threadIdx.x, lane = tid & 63, wv = tid >> 6;

    int nwg = gridDim.x, bid = blockIdx.x;
    int qq = nwg >> 3, rr = nwg & 7;
    int xcd = bid & 7, idx = bid >> 3;
    int newid = (xcd < rr ? xcd * (qq + 1) : rr * (qq + 1) + (xcd - rr) * qq) + idx;

    int bm = (newid / NB) * 64, bn = (newid % NB) * 128;
    int wn = wv * 32;
    f32x4 acc[4][2] = {};

    int sr = tid >> 3, sc = tid & 7;
    int c_log = sc ^ (sr & 7);
    const short* Ag = (const short*)A + (long)(bm + sr) * K + (c_log << 3);
    const short* Bg = (const short*)W + (long)(bn + sr) * K + (c_log << 3);
    const long K32 = (long)32 * K;

    int lg = lane >> 4, lr16 = lane & 15;
    int aoff[2][4], boff[2][2];
    #pragma unroll
    for (int s = 0; s < 2; ++s) {
        #pragma unroll
        for (int i = 0; i < 4; ++i) {
            int ra = i * 16 + lr16;
            aoff[s][i] = (ra << 6) + ((((s << 2) | lg) ^ (ra & 7)) << 3);
        }
        #pragma unroll
        for (int j = 0; j < 2; ++j) {
            int rb = wn + j * 16 + lr16;
            boff[s][j] = (rb << 6) + ((((s << 2) | lg) ^ (rb & 7)) << 3);
        }
    }

    const int KT = K >> 6;
    {
        char* Ad = (char*)&As[0][0]; char* Bd = (char*)&Bs[0][0];
        gl2lds16(Ag,           Ad + tid * 16);
        gl2lds16(Ag + K32,     Ad + 4096 + tid * 16);
        gl2lds16(Bg,           Bd + tid * 16);
        gl2lds16(Bg + K32,     Bd + 4096 + tid * 16);
        gl2lds16(Bg + 2 * K32, Bd + 8192 + tid * 16);
        gl2lds16(Bg + 3 * K32, Bd + 12288 + tid * 16);
    }
    __syncthreads();

    for (int t = 0; t < KT; ++t) {
        if (t + 1 < KT) {
            int ktn = (t + 1) << 6;
            char* Ad = (char*)&As[(t & 1) ^ 1][0];
            char* Bd = (char*)&Bs[(t & 1) ^ 1][0];
            gl2lds16(Ag + ktn,           Ad + tid * 16);
            gl2lds16(Ag + K32 + ktn,     Ad + 4096 + tid * 16);
            gl2lds16(Bg + ktn,           Bd + tid * 16);
            gl2lds16(Bg + K32 + ktn,     Bd + 4096 + tid * 16);
            gl2lds16(Bg + 2 * K32 + ktn, Bd + 8192 + tid * 16);
            gl2lds16(Bg + 3 * K32 + ktn, Bd + 12288 + tid * 16);
        }
        const short* Ab = &As[t & 1][0];
        const short* Bb = &Bs[t & 1][0];
        #pragma unroll
        for (int s = 0; s < 2; ++s) {
            bf16x8 af[4], bfr[2];
            #pragma unroll
            for (int i = 0; i < 4; ++i)
                af[i] = *reinterpret_cast<const bf16x8*>(&Ab[aoff[s][i]]);
            #pragma unroll
            for (int j = 0; j < 2; ++j)
                bfr[j] = *reinterpret_cast<const bf16x8*>(&Bb[boff[s][j]]);
            #pragma unroll
            for (int mi = 0; mi < 4; ++mi)
                #pragma unroll
                for (int ni = 0; ni < 2; ++ni)
                    acc[mi][ni] = __builtin_amdgcn_mfma_f32_16x16x32_bf16(
                        af[mi], bfr[ni], acc[mi][ni], 0, 0, 0);
        }
        __syncthreads();
    }

    #pragma unroll
    for (int mi = 0; mi < 4; ++mi) {
        int row0 = bm + mi * 16 + (lane >> 4) * 4;
        #pragma unroll
        for (int ni = 0; ni < 2; ++ni) {
            int col = bn + wn + ni * 16 + lr16;
            #pragma unroll
            for (int r = 0; r < 4; ++r) {
                int row = row0 + r;
                if (row >= M) continue;
                float v = acc[mi][ni][r];
                if (MODE == M_PATCH) {
                    int pb = row / 196, pp = row - pb * 196;
                    Cf[((long)(pb * SEQ + 1 + pp)) * DMODEL + col] =
                        v + pos[(long)(1 + pp) * DMODEL + col];
                } else {
                    v += bias[col];
                    long idx2 = (long)row * N + col;
                    if (MODE == M_F32)      Cf[idx2] = v;
                    else if (MODE == M_ACC) Cf[idx2] += v;
                    else if (MODE == M_QKVB) Cb[idx2] = __float2bfloat16(v);
                    else if (MODE == M_GELU)
                        Cb[idx2] = __float2bfloat16(v / (1.f + __expf(-1.702f * v)));
                }
            }
        }
    }
}

// ---------------------------------------------------------------- attention
__global__ __launch_bounds__(256) void attn_kernel(
    const __hip_bfloat16* __restrict__ qkv, __hip_bfloat16* __restrict__ o)
{
    int bh = blockIdx.x;
    int b = bh / NHEADS, h = bh % NHEADS;
    int tid = threadIdx.x, lane = tid & 63, wv = tid >> 6;
    __shared__ short Ks[SPAD * 64];
    __shared__ short Vt[64 * VSTR];
    __shared__ short Ps[4][16 * VSTR];
    const short* base = (const short*)qkv + (long)b * SEQ * 2304;

    for (int idx = tid; idx < SPAD * 8; idx += 256) {
        int r = idx >> 3, c = idx & 7;
        int4 val = make_int4(0, 0, 0, 0);
        if (r < SEQ)
            val = *reinterpret_cast<const int4*>(base + (long)r * 2304 + 768 + h * 64 + c * 8);
        *reinterpret_cast<int4*>(&Ks[r * 64 + ((c ^ (r & 7)) << 3)]) = val;
    }
    for (int idx = tid; idx < SPAD * 64; idx += 256) {
        int k = idx >> 6, d = idx & 63;
        short v = (k < SEQ) ? base[(long)k * 2304 + 1536 + h * 64 + d] : (short)0;
        Vt[d * VSTR + k] = v;
    }
    __syncthreads();

    int lg = lane >> 4, lr = lane & 15;
    short* Pw = Ps[wv];

    for (int ch = wv; ch < 13; ch += 4) {
        int q0 = ch * 16;
        const short* qp = (const short*)qkv +
            ((long)(b * SEQ) + q0 + lr) * 2304 + h * 64 + (lg << 3);
        bf16x8 qa = *reinterpret_cast<const bf16x8*>(qp);
        bf16x8 qb = *reinterpret_cast<const bf16x8*>(qp + 32);

        f32x4 sc[13];
        #pragma unroll
        for (int f = 0; f < 13; ++f) sc[f] = (f32x4){0.f, 0.f, 0.f, 0.f};
        #pragma unroll
        for (int f = 0; f < 13; ++f) {
            int row = f * 16 + lr;
            int sw = row & 7;
            const short* kr = &Ks[row * 64];
            bf16x8 k0 = *reinterpret_cast<const bf16x8*>(&kr[((lg + 0) ^ sw) << 3]);
            bf16x8 k1 = *reinterpret_cast<const bf16x8*>(&kr[((lg + 4) ^ sw) << 3]);
            sc[f] = __builtin_amdgcn_mfma_f32_16x16x32_bf16(qa, k0, sc[f], 0, 0, 0);
            sc[f] = __builtin_amdgcn_mfma_f32_16x16x32_bf16(qb, k1, sc[f], 0, 0, 0);
        }

        float mrow[4] = {-1e30f, -1e30f, -1e30f, -1e30f};
        #pragma unroll
        for (int f = 0; f < 13; ++f) {
            bool ok = f * 16 + lr < SEQ;
            #pragma unroll
            for (int r = 0; r < 4; ++r)
                if (ok) mrow[r] = fmaxf(mrow[r], sc[f][r] * 0.125f);
        }
        #pragma unroll
        for (int r = 0; r < 4; ++r)
            #pragma unroll
            for (int off = 8; off; off >>= 1)
                mrow[r] = fmaxf(mrow[r], __shfl_xor(mrow[r], off));
        float esum[4] = {0.f, 0.f, 0.f, 0.f};
        #pragma unroll
        for (int f = 0; f < 13; ++f) {
            bool ok = f * 16 + lr < SEQ;
            #pragma unroll
            for (int r = 0; r < 4; ++r) {
                float e = ok ? __expf(sc[f][r] * 0.125f - mrow[r]) : 0.f;
                sc[f][r] = e;
                esum[r] += e;
            }
        }
        #pragma unroll
        for (int r = 0; r < 4; ++r)
            #pragma unroll
            for (int off = 8; off; off >>= 1)
                esum[r] += __shfl_xor(esum[r], off);
        float inv[4];
        #pragma unroll
        for (int r = 0; r < 4; ++r) inv[r] = 1.0f / esum[r];

        #pragma unroll
        for (int f = 0; f < 13; ++f)
            #pragma unroll
            for (int r = 0; r < 4; ++r)
                Pw[(lg * 4 + r) * VSTR + f * 16 + lr] = f2b(sc[f][r] * inv[r]);

        f32x4 oa[4] = {};
        #pragma unroll
        for (int ks = 0; ks < 7; ++ks) {
            int kb = ks * 32 + (lg << 3);
            bf16x8 pa = {};
            if (kb < SPAD) pa = *reinterpret_cast<const bf16x8*>(&Pw[lr * VSTR + kb]);
            #pragma unroll
            for (int d = 0; d < 4; ++d) {
                bf16x8 vb = {};
                if (kb < SPAD)
                    vb = *reinterpret_cast<const bf16x8*>(&Vt[(d * 16 + lr) * VSTR + kb]);
                oa[d] = __builtin_amdgcn_mfma_f32_16x16x32_bf16(pa, vb, oa[d], 0, 0, 0);
            }
        }

        #pragma unroll
        for (int d = 0; d < 4; ++d)
            #pragma unroll
            for (int r = 0; r < 4; ++r) {
                int q = q0 + lg * 4 + r;
                if (q < SEQ)
                    o[((long)(b * SEQ + q)) * DMODEL + h * 64 + d * 16 + lr] =
                        __float2bfloat16(oa[d][r]);
            }
    }
}

// ---------------------------------------------------------------- final proj
__global__ __launch_bounds__(256) void proj_kernel(
    const float* __restrict__ cls_ln, const float* __restrict__ proj,
    float* __restrict__ out)
{
    int idx = blockIdx.x * 256 + threadIdx.x;
    int m = idx >> 9, n = idx & 511;
    float s = 0.f;
    #pragma unroll 8
    for (int k = 0; k < 768; ++k)
        s += cls_ln[m * 768 + k] * proj[k * 512 + n];
    out[idx] = s;
}

// ---------------------------------------------------------------- launcher
extern "C" void kernel_launch(void* const* d_in, const int* in_sizes, int n_in,
                              void* d_out, int out_size, void* d_ws, size_t ws_size,
                              hipStream_t stream) {
    const float* x_inp    = (const float*)d_in[0];
    const float* conv_w   = (const float*)d_in[1];
    const float* cls_emb  = (const float*)d_in[2];
    const float* pos_emb  = (const float*)d_in[3];
    const float* ln_pre_w = (const float*)d_in[4];
    const float* ln_pre_b = (const float*)d_in[5];
    const float* ln1_w    = (const float*)d_in[6];
    const float* ln1_b    = (const float*)d_in[7];
    const float* qkv_w    = (const float*)d_in[8];
    const float* qkv_b    = (const float*)d_in[9];
    const float* out_w    = (const float*)d_in[10];
    const float* out_b    = (const float*)d_in[11];
    const float* ln2_w    = (const float*)d_in[12];
    const float* ln2_b    = (const float*)d_in[13];
    const float* fc1_w    = (const float*)d_in[14];
    const float* fc1_b    = (const float*)d_in[15];
    const float* fc2_w    = (const float*)d_in[16];
    const float* fc2_b    = (const float*)d_in[17];
    const float* ln_post_w= (const float*)d_in[18];
    const float* ln_post_b= (const float*)d_in[19];
    const float* proj     = (const float*)d_in[20];

    char* w = (char*)d_ws;
    __hip_bfloat16* wqkv = (__hip_bfloat16*)w; w += (size_t)LAYERS * 2304 * DMODEL * 2;
    __hip_bfloat16* wout = (__hip_bfloat16*)w; w += (size_t)LAYERS * DMODEL * DMODEL * 2;
    __hip_bfloat16* wfc1 = (__hip_bfloat16*)w; w += (size_t)LAYERS * FFDIM * DMODEL * 2;
    __hip_bfloat16* wfc2 = (__hip_bfloat16*)w; w += (size_t)LAYERS * DMODEL * FFDIM * 2;
    __hip_bfloat16* wconv= (__hip_bfloat16*)w; w += (size_t)DMODEL * DMODEL * 2;
    float* x             = (float*)w;          w += (size_t)MROWS * DMODEL * 4;
    __hip_bfloat16* y    = (__hip_bfloat16*)w; w += (size_t)MPAD * DMODEL * 2;
    __hip_bfloat16* qkvb = (__hip_bfloat16*)w; w += (size_t)MPAD * 2304 * 2;
    __hip_bfloat16* attno= (__hip_bfloat16*)w; w += (size_t)MPAD * DMODEL * 2;
    __hip_bfloat16* h1   = (__hip_bfloat16*)w; w += (size_t)MPAD * FFDIM * 2;
    __hip_bfloat16* patches = (__hip_bfloat16*)w; w += (size_t)NPATCH * BATCH * DMODEL * 2;
    float* clsb          = (float*)w;          w += (size_t)BATCH * DMODEL * 4;

    cvt_bf16_kernel<<<2048, 256, 0, stream>>>(qkv_w, wqkv, (long)LAYERS * 2304 * DMODEL);
    cvt_bf16_kernel<<<2048, 256, 0, stream>>>(out_w, wout, (long)LAYERS * DMODEL * DMODEL);
    cvt_bf16_kernel<<<2048, 256, 0, stream>>>(fc1_w, wfc1, (long)LAYERS * FFDIM * DMODEL);
    cvt_bf16_kernel<<<2048, 256, 0, stream>>>(fc2_w, wfc2, (long)LAYERS * DMODEL * FFDIM);
    cvt_bf16_kernel<<<512, 256, 0, stream>>>(conv_w, wconv, (long)DMODEL * DMODEL);

    im2col_kernel<<<NPATCH * BATCH, 256, 0, stream>>>(x_inp, patches);
    gemm_bf16<M_PATCH><<<98 * 6, 256, 0, stream>>>(
        patches, wconv, nullptr, x, nullptr, NPATCH * BATCH, DMODEL, DMODEL, 6, pos_emb);
    cls_token_kernel<<<BATCH, 256, 0, stream>>>(cls_emb, pos_emb, x);
    ln_kernel<0><<<MROWS / 4, 256, 0, stream>>>(x, x, ln_pre_w, ln_pre_b,
                                                DMODEL, DMODEL, MROWS);

    for (int l = 0; l < LAYERS; ++l) {
        ln_kernel<1><<<MROWS / 4, 256, 0, stream>>>(x, y, ln1_w + l * DMODEL,
                                                    ln1_b + l * DMODEL, DMODEL, DMODEL, MROWS);
        gemm_bf16<M_QKVB><<<99 * 18, 256, 0, stream>>>(
            y, wqkv + (long)l * 2304 * DMODEL, qkv_b + (long)l * 2304, nullptr, qkvb,
            MROWS, 2304, DMODEL, 18, nullptr);
        attn_kernel<<<BATCH * NHEADS, 256, 0, stream>>>(qkvb, attno);
        gemm_bf16<M_ACC><<<99 * 6, 256, 0, stream>>>(
            attno, wout + (long)l * DMODEL * DMODEL, out_b + (long)l * DMODEL, x, nullptr,
            MROWS, DMODEL, DMODEL, 6, nullptr);
        ln_kernel<1><<<MROWS / 4, 256, 0, stream>>>(x, y, ln2_w + l * DMODEL,
                                                    ln2_b + l * DMODEL, DMODEL, DMODEL, MROWS);
        gemm_bf16<M_GELU><<<99 * 24, 256, 0, stream>>>(
            y, wfc1 + (long)l * FFDIM * DMODEL, fc1_b + (long)l * FFDIM, nullptr, h1,
            MROWS, FFDIM, DMODEL, 24, nullptr);
        gemm_bf16<M_ACC><<<99 * 6, 256, 0, stream>>>(
            h1, wfc2 + (long)l * DMODEL * FFDIM, fc2_b + (long)l * DMODEL, x, nullptr,
            MROWS, DMODEL, FFDIM, 6, nullptr);
    }

    ln_kernel<0><<<8, 256, 0, stream>>>(x, clsb, ln_post_w, ln_post_b,
                                        (long)SEQ * DMODEL, DMODEL, BATCH);
    proj_kernel<<<(BATCH * OUTD) / 256, 256, 0, stream>>>(clsb, proj, (float*)d_out);
}

// Round 13
// 3182.264 us; speedup vs baseline: 1.5507x; 1.0695x over previous
//
#include <hip/hip_runtime.h>
#include <hip/hip_bf16.h>

// CLIP ViT-B/16 visual forward — Round 13: qkv/fc1 use NEW single-buffer
// 128x128 BK=64 GEMM (32KB LDS -> 5 blocks/CU co-residency; 2x2 waves of
// 64x64 -> best FLOP/LDS-byte). fc2/out/patch keep R8 64x128 2-buf kernel.
// Wave-per-row LN (R12). Attention unchanged.

#define LAYERS 12
#define DMODEL 768
#define NHEADS 12
#define DHEAD  64
#define FFDIM  3072
#define BATCH  32
#define SEQ    197
#define NPATCH 196
#define OUTD   512
#define MROWS  (BATCH * SEQ)   // 6304
#define MPAD   6400
#define SPAD   208
#define VSTR   208

typedef __attribute__((ext_vector_type(4))) float f32x4;
typedef __attribute__((ext_vector_type(8))) short bf16x8;

enum { M_F32 = 0, M_ACC = 1, M_GELU = 2, M_PATCH = 3, M_QKVB = 4 };

__device__ __forceinline__ float b2f(short s) {
    unsigned u = ((unsigned)(unsigned short)s) << 16;
    return __builtin_bit_cast(float, u);
}
__device__ __forceinline__ short f2b(float f) {
    __hip_bfloat16 h = __float2bfloat16(f);
    return __builtin_bit_cast(short, h);
}
__device__ __forceinline__ unsigned short f2bu(float f) {
    __hip_bfloat16 h = __float2bfloat16(f);
    return __builtin_bit_cast(unsigned short, h);
}

__device__ __forceinline__ void gl2lds16(const void* g, void* l) {
    __builtin_amdgcn_global_load_lds(
        (const __attribute__((address_space(1))) void*)g,
        (__attribute__((address_space(3))) void*)l, 16, 0, 0);
}

// ---------------------------------------------------------------- weight cvt
__global__ __launch_bounds__(256) void cvt_bf16_kernel(
    const float* __restrict__ src, __hip_bfloat16* __restrict__ dst, long n)
{
    long i0 = ((long)blockIdx.x * 256 + threadIdx.x) * 4;
    long stride = (long)gridDim.x * 1024;
    for (long i = i0; i < n; i += stride) {
        float4 v = *reinterpret_cast<const float4*>(&src[i]);
        dst[i + 0] = __float2bfloat16(v.x);
        dst[i + 1] = __float2bfloat16(v.y);
        dst[i + 2] = __float2bfloat16(v.z);
        dst[i + 3] = __float2bfloat16(v.w);
    }
}

// ---------------------------------------------------------------- im2col
__global__ __launch_bounds__(256) void im2col_kernel(
    const float* __restrict__ x_inp, __hip_bfloat16* __restrict__ patches)
{
    int bp = blockIdx.x;
    int b = bp / NPATCH, p = bp % NPATCH;
    int py = p / 14, px = p % 14;
    const float* xb = x_inp + (long)b * 3 * 224 * 224;
    for (int e = threadIdx.x; e < 768; e += 256) {
        int c = e >> 8, i = (e >> 4) & 15, j = e & 15;
        patches[(long)bp * 768 + e] =
            __float2bfloat16(xb[((long)c * 224 + py * 16 + i) * 224 + px * 16 + j]);
    }
}

__global__ __launch_bounds__(256) void cls_token_kernel(
    const float* __restrict__ cls_emb, const float* __restrict__ pos_emb,
    float* __restrict__ x)
{
    int b = blockIdx.x;
    for (int d = threadIdx.x; d < DMODEL; d += 256)
        x[(long)b * SEQ * DMODEL + d] = cls_emb[d] + pos_emb[d];
}

// ---------------------------------------------------------------- layernorm
// one WAVE per row; 4 rows per 256-thread block (R12).
template<int OB>
__global__ __launch_bounds__(256) void ln_kernel(
    const float* __restrict__ in, void* __restrict__ out,
    const float* __restrict__ w, const float* __restrict__ bb,
    long in_stride, long out_stride, int nrows)
{
    int row = blockIdx.x * 4 + (threadIdx.x >> 6);
    if (row >= nrows) return;
    int lane = threadIdx.x & 63;
    const float* xr = in + (long)row * in_stride;

    float4 v[3];
    float s = 0.f;
    #pragma unroll
    for (int i = 0; i < 3; ++i) {
        v[i] = *reinterpret_cast<const float4*>(&xr[i * 256 + lane * 4]);
        s += v[i].x + v[i].y + v[i].z + v[i].w;
    }
    #pragma unroll
    for (int off = 32; off; off >>= 1) s += __shfl_xor(s, off);
    float mean = s * (1.0f / DMODEL);
    float sq = 0.f;
    #pragma unroll
    for (int i = 0; i < 3; ++i) {
        float a = v[i].x - mean, b2 = v[i].y - mean,
              c = v[i].z - mean, d = v[i].w - mean;
        sq += a * a + b2 * b2 + c * c + d * d;
    }
    #pragma unroll
    for (int off = 32; off; off >>= 1) sq += __shfl_xor(sq, off);
    float rstd = rsqrtf(sq * (1.0f / DMODEL) + 1e-5f);

    #pragma unroll
    for (int i = 0; i < 3; ++i) {
        int d0 = i * 256 + lane * 4;
        float4 wv = *reinterpret_cast<const float4*>(&w[d0]);
        float4 bv = *reinterpret_cast<const float4*>(&bb[d0]);
        float o0 = (v[i].x - mean) * rstd * wv.x + bv.x;
        float o1 = (v[i].y - mean) * rstd * wv.y + bv.y;
        float o2 = (v[i].z - mean) * rstd * wv.z + bv.z;
        float o3 = (v[i].w - mean) * rstd * wv.w + bv.w;
        if (OB) {
            ushort4 u;
            u.x = f2bu(o0); u.y = f2bu(o1); u.z = f2bu(o2); u.w = f2bu(o3);
            *reinterpret_cast<ushort4*>(
                &((__hip_bfloat16*)out)[(long)row * out_stride + d0]) = u;
        } else {
            float4 o = make_float4(o0, o1, o2, o3);
            *reinterpret_cast<float4*>(&((float*)out)[(long)row * out_stride + d0]) = o;
        }
    }
}

// ---------------------------------------------------------------- GEMM (R8)
// 64x128 tile, BK=64, 2-buffer 48KB LDS, chunk^=row&7 swizzle — for the
// small-grid GEMMs (fc2/out/patch).
template<int MODE>
__global__ __launch_bounds__(256) void gemm_bf16(
    const __hip_bfloat16* __restrict__ A, const __hip_bfloat16* __restrict__ W,
    const float* __restrict__ bias, float* __restrict__ Cf,
    __hip_bfloat16* __restrict__ Cb, int M, int N, int K, int NB,
    const float* __restrict__ pos)
{
    __shared__ short As[2][64 * 64];
    __shared__ short Bs[2][128 * 64];
    int tid = threadIdx.x, lane = tid & 63, wv = tid >> 6;

    int nwg = gridDim.x, bid = blockIdx.x;
    int qq = nwg >> 3, rr = nwg & 7;
    int xcd = bid & 7, idx = bid >> 3;
    int newid = (xcd < rr ? xcd * (qq + 1) : rr * (qq + 1) + (xcd - rr) * qq) + idx;

    int bm = (newid / NB) * 64, bn = (newid % NB) * 128;
    int wn = wv * 32;
    f32x4 acc[4][2] = {};

    int sr = tid >> 3, sc = tid & 7;
    int c_log = sc ^ (sr & 7);
    const short* Ag = (const short*)A + (long)(bm + sr) * K + (c_log << 3);
    const short* Bg = (const short*)W + (long)(bn + sr) * K + (c_log << 3);
    const long K32 = (long)32 * K;

    int lg = lane >> 4, lr16 = lane & 15;
    int aoff[2][4], boff[2][2];
    #pragma unroll
    for (int s = 0; s < 2; ++s) {
        #pragma unroll
        for (int i = 0; i < 4; ++i) {
            int ra = i * 16 + lr16;
            aoff[s][i] = (ra << 6) + ((((s << 2) | lg) ^ (ra & 7)) << 3);
        }
        #pragma unroll
        for (int j = 0; j < 2; ++j) {
            int rb = wn + j * 16 + lr16;
            boff[s][j] = (rb << 6) + ((((s << 2) | lg) ^ (rb & 7)) << 3);
        }
    }

    const int KT = K >> 6;
    {
        char* Ad = (char*)&As[0][0]; char* Bd = (char*)&Bs[0][0];
        gl2lds16(Ag,           Ad + tid * 16);
        gl2lds16(Ag + K32,     Ad + 4096 + tid * 16);
        gl2lds16(Bg,           Bd + tid * 16);
        gl2lds16(Bg + K32,     Bd + 4096 + tid * 16);
        gl2lds16(Bg + 2 * K32, Bd + 8192 + tid * 16);
        gl2lds16(Bg + 3 * K32, Bd + 12288 + tid * 16);
    }
    __syncthreads();

    for (int t = 0; t < KT; ++t) {
        if (t + 1 < KT) {
            int ktn = (t + 1) << 6;
            char* Ad = (char*)&As[(t & 1) ^ 1][0];
            char* Bd = (char*)&Bs[(t & 1) ^ 1][0];
            gl2lds16(Ag + ktn,           Ad + tid * 16);
            gl2lds16(Ag + K32 + ktn,     Ad + 4096 + tid * 16);
            gl2lds16(Bg + ktn,           Bd + tid * 16);
            gl2lds16(Bg + K32 + ktn,     Bd + 4096 + tid * 16);
            gl2lds16(Bg + 2 * K32 + ktn, Bd + 8192 + tid * 16);
            gl2lds16(Bg + 3 * K32 + ktn, Bd + 12288 + tid * 16);
        }
        const short* Ab = &As[t & 1][0];
        const short* Bb = &Bs[t & 1][0];
        #pragma unroll
        for (int s = 0; s < 2; ++s) {
            bf16x8 af[4], bfr[2];
            #pragma unroll
            for (int i = 0; i < 4; ++i)
                af[i] = *reinterpret_cast<const bf16x8*>(&Ab[aoff[s][i]]);
            #pragma unroll
            for (int j = 0; j < 2; ++j)
                bfr[j] = *reinterpret_cast<const bf16x8*>(&Bb[boff[s][j]]);
            #pragma unroll
            for (int mi = 0; mi < 4; ++mi)
                #pragma unroll
                for (int ni = 0; ni < 2; ++ni)
                    acc[mi][ni] = __builtin_amdgcn_mfma_f32_16x16x32_bf16(
                        af[mi], bfr[ni], acc[mi][ni], 0, 0, 0);
        }
        __syncthreads();
    }

    #pragma unroll
    for (int mi = 0; mi < 4; ++mi) {
        int row0 = bm + mi * 16 + (lane >> 4) * 4;
        #pragma unroll
        for (int ni = 0; ni < 2; ++ni) {
            int col = bn + wn + ni * 16 + lr16;
            #pragma unroll
            for (int r = 0; r < 4; ++r) {
                int row = row0 + r;
                if (row >= M) continue;
                float v = acc[mi][ni][r];
                if (MODE == M_PATCH) {
                    int pb = row / 196, pp = row - pb * 196;
                    Cf[((long)(pb * SEQ + 1 + pp)) * DMODEL + col] =
                        v + pos[(long)(1 + pp) * DMODEL + col];
                } else {
                    v += bias[col];
                    long idx2 = (long)row * N + col;
                    if (MODE == M_F32)      Cf[idx2] = v;
                    else if (MODE == M_ACC) Cf[idx2] += v;
                    else if (MODE == M_QKVB) Cb[idx2] = __float2bfloat16(v);
                    else if (MODE == M_GELU)
                        Cb[idx2] = __float2bfloat16(v / (1.f + __expf(-1.702f * v)));
                }
            }
        }
    }
}

// ---------------------------------------------------------------- GEMM 128sq
// NEW: 128x128 tile, BK=64, SINGLE-buffer 32KB LDS (5 blocks/CU), 4 waves
// (2x2) each 64x64 out: per block-step 2 MFLOP for 96KB LDS traffic (1.5x
// less than R8 structure). Cross-block overlap hides the per-step stage
// serialization. For qkv (grid 900) / fc1 (grid 1200) only.
template<int MODE>
__global__ __launch_bounds__(256) void gemm128(
    const __hip_bfloat16* __restrict__ A, const __hip_bfloat16* __restrict__ W,
    const float* __restrict__ bias, __hip_bfloat16* __restrict__ Cb,
    int M, int N, int K, int NB)
{
    __shared__ short As[128 * 64];   // 16KB
    __shared__ short Bs[128 * 64];   // 16KB
    int tid = threadIdx.x, lane = tid & 63, wv = tid >> 6;

    int nwg = gridDim.x, bid = blockIdx.x;
    int qq = nwg >> 3, rr = nwg & 7;
    int xcd = bid & 7, idx = bid >> 3;
    int newid = (xcd < rr ? xcd * (qq + 1) : rr * (qq + 1) + (xcd - rr) * qq) + idx;

    int bm = (newid / NB) * 128, bn = (newid % NB) * 128;
    int wr = wv >> 1, wc = wv & 1;
    f32x4 acc[4][4] = {};

    // staging: thread t -> (row sr = t/8, chunk slot sc = t%8), 4 passes of
    // 32 rows each for A and B; slot sc holds logical chunk sc ^ (sr&7).
    int sr = tid >> 3, scn = tid & 7;
    int c_log = scn ^ (sr & 7);
    const short* Ag = (const short*)A + (long)(bm + sr) * K + (c_log << 3);
    const short* Bg = (const short*)W + (long)(bn + sr) * K + (c_log << 3);
    const long K32 = (long)32 * K;

    int lg = lane >> 4, lr16 = lane & 15;
    int aoff[2][4], boff[2][4];
    #pragma unroll
    for (int s = 0; s < 2; ++s) {
        int kc = (s << 2) | lg;
        #pragma unroll
        for (int i = 0; i < 4; ++i) {
            int ra = wr * 64 + i * 16 + lr16;
            aoff[s][i] = (ra << 6) + ((kc ^ (ra & 7)) << 3);
            int rb = wc * 64 + i * 16 + lr16;
            boff[s][i] = (rb << 6) + ((kc ^ (rb & 7)) << 3);
        }
    }

    const int KT = K >> 6;
    for (int t = 0; t < KT; ++t) {
        if (t) __syncthreads();      // all reads of the buffer done
        int kt = t << 6;
        #pragma unroll
        for (int p = 0; p < 4; ++p) {
            gl2lds16(Ag + p * K32 + kt, (char*)As + p * 4096 + tid * 16);
            gl2lds16(Bg + p * K32 + kt, (char*)Bs + p * 4096 + tid * 16);
        }
        __syncthreads();             // vmcnt(0) drain + publish

        #pragma unroll
        for (int s = 0; s < 2; ++s) {
            bf16x8 af[4], bfr[4];
            #pragma unroll
            for (int i = 0; i < 4; ++i)
                af[i] = *reinterpret_cast<const bf16x8*>(&As[aoff[s][i]]);
            #pragma unroll
            for (int j = 0; j < 4; ++j)
                bfr[j] = *reinterpret_cast<const bf16x8*>(&Bs[boff[s][j]]);
            #pragma unroll
            for (int mi = 0; mi < 4; ++mi)
                #pragma unroll
                for (int ni = 0; ni < 4; ++ni)
                    acc[mi][ni] = __builtin_amdgcn_mfma_f32_16x16x32_bf16(
                        af[mi], bfr[ni], acc[mi][ni], 0, 0, 0);
        }
    }

    #pragma unroll
    for (int mi = 0; mi < 4; ++mi) {
        int row0 = bm + wr * 64 + mi * 16 + lg * 4;
        #pragma unroll
        for (int ni = 0; ni < 4; ++ni) {
            int col = bn + wc * 64 + ni * 16 + lr16;
            #pragma unroll
            for (int r = 0; r < 4; ++r) {
                int row = row0 + r;
                if (row >= M) continue;
                float v = acc[mi][ni][r] + bias[col];
                long idx2 = (long)row * N + col;
                if (MODE == M_QKVB) Cb[idx2] = __float2bfloat16(v);
                else                Cb[idx2] = __float2bfloat16(v / (1.f + __expf(-1.702f * v)));
            }
        }
    }
}

// ---------------------------------------------------------------- attention
__global__ __launch_bounds__(256) void attn_kernel(
    const __hip_bfloat16* __restrict__ qkv, __hip_bfloat16* __restrict__ o)
{
    int bh = blockIdx.x;
    int b = bh / NHEADS, h = bh % NHEADS;
    int tid = threadIdx.x, lane = tid & 63, wv = tid >> 6;
    __shared__ short Ks[SPAD * 64];
    __shared__ short Vt[64 * VSTR];
    __shared__ short Ps[4][16 * VSTR];
    const short* base = (const short*)qkv + (long)b * SEQ * 2304;

    for (int idx = tid; idx < SPAD * 8; idx += 256) {
        int r = idx >> 3, c = idx & 7;
        int4 val = make_int4(0, 0, 0, 0);
        if (r < SEQ)
            val = *reinterpret_cast<const int4*>(base + (long)r * 2304 + 768 + h * 64 + c * 8);
        *reinterpret_cast<int4*>(&Ks[r * 64 + ((c ^ (r & 7)) << 3)]) = val;
    }
    for (int idx = tid; idx < SPAD * 64; idx += 256) {
        int k = idx >> 6, d = idx & 63;
        short v = (k < SEQ) ? base[(long)k * 2304 + 1536 + h * 64 + d] : (short)0;
        Vt[d * VSTR + k] = v;
    }
    __syncthreads();

    int lg = lane >> 4, lr = lane & 15;
    short* Pw = Ps[wv];

    for (int ch = wv; ch < 13; ch += 4) {
        int q0 = ch * 16;
        const short* qp = (const short*)qkv +
            ((long)(b * SEQ) + q0 + lr) * 2304 + h * 64 + (lg << 3);
        bf16x8 qa = *reinterpret_cast<const bf16x8*>(qp);
        bf16x8 qb = *reinterpret_cast<const bf16x8*>(qp + 32);

        f32x4 sc[13];
        #pragma unroll
        for (int f = 0; f < 13; ++f) sc[f] = (f32x4){0.f, 0.f, 0.f, 0.f};
        #pragma unroll
        for (int f = 0; f < 13; ++f) {
            int row = f * 16 + lr;
            int sw = row & 7;
            const short* kr = &Ks[row * 64];
            bf16x8 k0 = *reinterpret_cast<const bf16x8*>(&kr[((lg + 0) ^ sw) << 3]);
            bf16x8 k1 = *reinterpret_cast<const bf16x8*>(&kr[((lg + 4) ^ sw) << 3]);
            sc[f] = __builtin_amdgcn_mfma_f32_16x16x32_bf16(qa, k0, sc[f], 0, 0, 0);
            sc[f] = __builtin_amdgcn_mfma_f32_16x16x32_bf16(qb, k1, sc[f], 0, 0, 0);
        }

        float mrow[4] = {-1e30f, -1e30f, -1e30f, -1e30f};
        #pragma unroll
        for (int f = 0; f < 13; ++f) {
            bool ok = f * 16 + lr < SEQ;
            #pragma unroll
            for (int r = 0; r < 4; ++r)
                if (ok) mrow[r] = fmaxf(mrow[r], sc[f][r] * 0.125f);
        }
        #pragma unroll
        for (int r = 0; r < 4; ++r)
            #pragma unroll
            for (int off = 8; off; off >>= 1)
                mrow[r] = fmaxf(mrow[r], __shfl_xor(mrow[r], off));
        float esum[4] = {0.f, 0.f, 0.f, 0.f};
        #pragma unroll
        for (int f = 0; f < 13; ++f) {
            bool ok = f * 16 + lr < SEQ;
            #pragma unroll
            for (int r = 0; r < 4; ++r) {
                float e = ok ? __expf(sc[f][r] * 0.125f - mrow[r]) : 0.f;
                sc[f][r] = e;
                esum[r] += e;
            }
        }
        #pragma unroll
        for (int r = 0; r < 4; ++r)
            #pragma unroll
            for (int off = 8; off; off >>= 1)
                esum[r] += __shfl_xor(esum[r], off);
        float inv[4];
        #pragma unroll
        for (int r = 0; r < 4; ++r) inv[r] = 1.0f / esum[r];

        #pragma unroll
        for (int f = 0; f < 13; ++f)
            #pragma unroll
            for (int r = 0; r < 4; ++r)
                Pw[(lg * 4 + r) * VSTR + f * 16 + lr] = f2b(sc[f][r] * inv[r]);

        f32x4 oa[4] = {};
        #pragma unroll
        for (int ks = 0; ks < 7; ++ks) {
            int kb = ks * 32 + (lg << 3);
            bf16x8 pa = {};
            if (kb < SPAD) pa = *reinterpret_cast<const bf16x8*>(&Pw[lr * VSTR + kb]);
            #pragma unroll
            for (int d = 0; d < 4; ++d) {
                bf16x8 vb = {};
                if (kb < SPAD)
                    vb = *reinterpret_cast<const bf16x8*>(&Vt[(d * 16 + lr) * VSTR + kb]);
                oa[d] = __builtin_amdgcn_mfma_f32_16x16x32_bf16(pa, vb, oa[d], 0, 0, 0);
            }
        }

        #pragma unroll
        for (int d = 0; d < 4; ++d)
            #pragma unroll
            for (int r = 0; r < 4; ++r) {
                int q = q0 + lg * 4 + r;
                if (q < SEQ)
                    o[((long)(b * SEQ + q)) * DMODEL + h * 64 + d * 16 + lr] =
                        __float2bfloat16(oa[d][r]);
            }
    }
}

// ---------------------------------------------------------------- final proj
__global__ __launch_bounds__(256) void proj_kernel(
    const float* __restrict__ cls_ln, const float* __restrict__ proj,
    float* __restrict__ out)
{
    int idx = blockIdx.x * 256 + threadIdx.x;
    int m = idx >> 9, n = idx & 511;
    float s = 0.f;
    #pragma unroll 8
    for (int k = 0; k < 768; ++k)
        s += cls_ln[m * 768 + k] * proj[k * 512 + n];
    out[idx] = s;
}

// ---------------------------------------------------------------- launcher
extern "C" void kernel_launch(void* const* d_in, const int* in_sizes, int n_in,
                              void* d_out, int out_size, void* d_ws, size_t ws_size,
                              hipStream_t stream) {
    const float* x_inp    = (const float*)d_in[0];
    const float* conv_w   = (const float*)d_in[1];
    const float* cls_emb  = (const float*)d_in[2];
    const float* pos_emb  = (const float*)d_in[3];
    const float* ln_pre_w = (const float*)d_in[4];
    const float* ln_pre_b = (const float*)d_in[5];
    const float* ln1_w    = (const float*)d_in[6];
    const float* ln1_b    = (const float*)d_in[7];
    const float* qkv_w    = (const float*)d_in[8];
    const float* qkv_b    = (const float*)d_in[9];
    const float* out_w    = (const float*)d_in[10];
    const float* out_b    = (const float*)d_in[11];
    const float* ln2_w    = (const float*)d_in[12];
    const float* ln2_b    = (const float*)d_in[13];
    const float* fc1_w    = (const float*)d_in[14];
    const float* fc1_b    = (const float*)d_in[15];
    const float* fc2_w    = (const float*)d_in[16];
    const float* fc2_b    = (const float*)d_in[17];
    const float* ln_post_w= (const float*)d_in[18];
    const float* ln_post_b= (const float*)d_in[19];
    const float* proj     = (const float*)d_in[20];

    char* w = (char*)d_ws;
    __hip_bfloat16* wqkv = (__hip_bfloat16*)w; w += (size_t)LAYERS * 2304 * DMODEL * 2;
    __hip_bfloat16* wout = (__hip_bfloat16*)w; w += (size_t)LAYERS * DMODEL * DMODEL * 2;
    __hip_bfloat16* wfc1 = (__hip_bfloat16*)w; w += (size_t)LAYERS * FFDIM * DMODEL * 2;
    __hip_bfloat16* wfc2 = (__hip_bfloat16*)w; w += (size_t)LAYERS * DMODEL * FFDIM * 2;
    __hip_bfloat16* wconv= (__hip_bfloat16*)w; w += (size_t)DMODEL * DMODEL * 2;
    float* x             = (float*)w;          w += (size_t)MROWS * DMODEL * 4;
    __hip_bfloat16* y    = (__hip_bfloat16*)w; w += (size_t)MPAD * DMODEL * 2;
    __hip_bfloat16* qkvb = (__hip_bfloat16*)w; w += (size_t)MPAD * 2304 * 2;
    __hip_bfloat16* attno= (__hip_bfloat16*)w; w += (size_t)MPAD * DMODEL * 2;
    __hip_bfloat16* h1   = (__hip_bfloat16*)w; w += (size_t)MPAD * FFDIM * 2;
    __hip_bfloat16* patches = (__hip_bfloat16*)w; w += (size_t)NPATCH * BATCH * DMODEL * 2;
    float* clsb          = (float*)w;          w += (size_t)BATCH * DMODEL * 4;

    cvt_bf16_kernel<<<2048, 256, 0, stream>>>(qkv_w, wqkv, (long)LAYERS * 2304 * DMODEL);
    cvt_bf16_kernel<<<2048, 256, 0, stream>>>(out_w, wout, (long)LAYERS * DMODEL * DMODEL);
    cvt_bf16_kernel<<<2048, 256, 0, stream>>>(fc1_w, wfc1, (long)LAYERS * FFDIM * DMODEL);
    cvt_bf16_kernel<<<2048, 256, 0, stream>>>(fc2_w, wfc2, (long)LAYERS * DMODEL * FFDIM);
    cvt_bf16_kernel<<<512, 256, 0, stream>>>(conv_w, wconv, (long)DMODEL * DMODEL);

    im2col_kernel<<<NPATCH * BATCH, 256, 0, stream>>>(x_inp, patches);
    gemm_bf16<M_PATCH><<<98 * 6, 256, 0, stream>>>(
        patches, wconv, nullptr, x, nullptr, NPATCH * BATCH, DMODEL, DMODEL, 6, pos_emb);
    cls_token_kernel<<<BATCH, 256, 0, stream>>>(cls_emb, pos_emb, x);
    ln_kernel<0><<<MROWS / 4, 256, 0, stream>>>(x, x, ln_pre_w, ln_pre_b,
                                                DMODEL, DMODEL, MROWS);

    for (int l = 0; l < LAYERS; ++l) {
        ln_kernel<1><<<MROWS / 4, 256, 0, stream>>>(x, y, ln1_w + l * DMODEL,
                                                    ln1_b + l * DMODEL, DMODEL, DMODEL, MROWS);
        gemm128<M_QKVB><<<50 * 18, 256, 0, stream>>>(
            y, wqkv + (long)l * 2304 * DMODEL, qkv_b + (long)l * 2304, qkvb,
            MROWS, 2304, DMODEL, 18);
        attn_kernel<<<BATCH * NHEADS, 256, 0, stream>>>(qkvb, attno);
        gemm_bf16<M_ACC><<<99 * 6, 256, 0, stream>>>(
            attno, wout + (long)l * DMODEL * DMODEL, out_b + (long)l * DMODEL, x, nullptr,
            MROWS, DMODEL, DMODEL, 6, nullptr);
        ln_kernel<1><<<MROWS / 4, 256, 0, stream>>>(x, y, ln2_w + l * DMODEL,
                                                    ln2_b + l * DMODEL, DMODEL, DMODEL, MROWS);
        gemm128<M_GELU><<<50 * 24, 256, 0, stream>>>(
            y, wfc1 + (long)l * FFDIM * DMODEL, fc1_b + (long)l * FFDIM, h1,
            MROWS, FFDIM, DMODEL, 24);
        gemm_bf16<M_ACC><<<99 * 6, 256, 0, stream>>>(
            h1, wfc2 + (long)l * DMODEL * FFDIM, fc2_b + (long)l * DMODEL, x, nullptr,
            MROWS, DMODEL, FFDIM, 6, nullptr);
    }

    ln_kernel<0><<<8, 256, 0, stream>>>(x, clsb, ln_post_w, ln_post_b,
                                        (long)SEQ * DMODEL, DMODEL, BATCH);
    proj_kernel<<<(BATCH * OUTD) / 256, 256, 0, stream>>>(clsb, proj, (float*)d_out);
}